// Round 15
// baseline (223.237 us; speedup 1.0000x reference)
//
#include <hip/hip_runtime.h>

// Geometry: G=256 graphs x 64 nodes, H=8 heads x D=8, IN_DIM=EDGE_DIM=64
// EF = 1048576 full edges, ES = 262144 sparse edges.
// edge f = b*4096 + i*64 + j (src=i, dst=j); sparse s = b*1024 + j*16 + k, i=(j+1+k)&63.
//
// Staging (floats, in d_out's eout region, all dead before eoutT writes):
//   Qs @0, Ks @1048576, Vs @2097152, PEs @3145728,
//   relT @5242880 ([b][jh][i], 8.4M), adjT @13631488 ([b][j][i], 1M).
//   d_ws: scsp [262144*8] @0, M2 [576] @2097152, Tm [73*64] @2098176.
// NOTE r14 meta-result: attn stuck at ~60us across SIX structures whenever the
// inner loop had per-iteration narrow/scattered loads (per-lane-varying i).
// qkvpe (4.6 TB/s) differs only in: wide contiguous loads, issued in bulk.
// r15 fix: i-ORDER loop (wave-uniform i -> LDS broadcast K/V), rel/adj
// TRANSPOSED so each thread's 64 values are contiguous, prefetched to regs
// in one burst. Loop body = regs + LDS broadcast only, fully unrolled.

// qkv (blocks 0..255) + pe (256..767) + rel/adj transpose (768..1023).
__global__ __launch_bounds__(512, 2) void qkvpe_kernel(
    const float* __restrict__ h,
    const float* __restrict__ e,
    const float* __restrict__ adj2,
    const float* __restrict__ rel,
    const float* __restrict__ Wq, const float* __restrict__ bq,
    const float* __restrict__ Wk, const float* __restrict__ bk,
    const float* __restrict__ Wv, const float* __restrict__ bv,
    const float* __restrict__ Wpe, const float* __restrict__ bpe,
    float* __restrict__ Qs, float* __restrict__ Ks, float* __restrict__ Vs,
    float* __restrict__ PEs, float* __restrict__ relT, float* __restrict__ adjT)
{
    __shared__ float shA[64 * 65];   // adj transpose tile
    __shared__ float shR[8 * 576];   // rel transpose tile: [i8][g*9 + d]
    const int t = threadIdx.x;
    if (blockIdx.x < 256) {
        const int b    = blockIdx.x;
        const int lane = t & 63;
        const int wu   = __builtin_amdgcn_readfirstlane(t >> 6);   // 8 cols per wave
        const float* hrow = h + (size_t)(b * 64 + lane) * 64;
        float accQ[8], accK[8], accV[8];
        #pragma unroll
        for (int cc = 0; cc < 8; ++cc) {
            const int c = wu * 8 + cc;
            accQ[cc] = bq[c]; accK[cc] = bk[c]; accV[cc] = bv[c];
        }
        #pragma unroll 1
        for (int k0 = 0; k0 < 4; ++k0) {
            float hv[16];
            #pragma unroll
            for (int u = 0; u < 4; ++u) {
                const float4 x = ((const float4*)hrow)[k0 * 4 + u];
                hv[u*4+0] = x.x; hv[u*4+1] = x.y; hv[u*4+2] = x.z; hv[u*4+3] = x.w;
            }
            #pragma unroll
            for (int cc = 0; cc < 8; ++cc) {
                const int c = wu * 8 + cc;
                const float* wq  = Wq + c * 64 + k0 * 16;   // wave-uniform -> s_load
                const float* wk  = Wk + c * 64 + k0 * 16;
                const float* wvp = Wv + c * 64 + k0 * 16;
                #pragma unroll
                for (int k = 0; k < 16; ++k) {
                    accQ[cc] = fmaf(hv[k], wq[k],  accQ[cc]);
                    accK[cc] = fmaf(hv[k], wk[k],  accK[cc]);
                    accV[cc] = fmaf(hv[k], wvp[k], accV[cc]);
                }
            }
        }
        const size_t o = (size_t)(b * 64 + lane) * 64 + wu * 8;
        *(float4*)(Qs + o)     = make_float4(accQ[0], accQ[1], accQ[2], accQ[3]);
        *(float4*)(Qs + o + 4) = make_float4(accQ[4], accQ[5], accQ[6], accQ[7]);
        *(float4*)(Ks + o)     = make_float4(accK[0], accK[1], accK[2], accK[3]);
        *(float4*)(Ks + o + 4) = make_float4(accK[4], accK[5], accK[6], accK[7]);
        *(float4*)(Vs + o)     = make_float4(accV[0], accV[1], accV[2], accV[3]);
        *(float4*)(Vs + o + 4) = make_float4(accV[4], accV[5], accV[6], accV[7]);
    } else if (blockIdx.x < 768) {
        const int row = (blockIdx.x - 256) * 512 + t;      // 0..ES-1
        const float* erow = e + (size_t)row * 64;
        float acc[8];
        #pragma unroll
        for (int h2 = 0; h2 < 8; ++h2) acc[h2] = bpe[h2];
        #pragma unroll 1
        for (int k0 = 0; k0 < 4; ++k0) {
            float ev[16];
            #pragma unroll
            for (int u = 0; u < 4; ++u) {
                const float4 x = ((const float4*)erow)[k0 * 4 + u];
                ev[u*4+0] = x.x; ev[u*4+1] = x.y; ev[u*4+2] = x.z; ev[u*4+3] = x.w;
            }
            #pragma unroll
            for (int h2 = 0; h2 < 8; ++h2) {
                const float* wp = Wpe + h2 * 64 + k0 * 16;  // uniform -> s_load
                #pragma unroll
                for (int k = 0; k < 16; ++k)
                    acc[h2] = fmaf(ev[k], wp[k], acc[h2]);
            }
        }
        float* p0 = PEs + (size_t)row * 8;
        *(float4*)(p0)     = make_float4(acc[0], acc[1], acc[2], acc[3]);
        *(float4*)(p0 + 4) = make_float4(acc[4], acc[5], acc[6], acc[7]);
    } else {
        // ---- transpose adj [i][j] -> adjT [j][i] and rel [i][jh] -> relT [jh][i]
        const int b = blockIdx.x - 768;
        {
            const float* ap = adj2 + (size_t)b * 4096 + t * 8;   // i=t>>3, j=(t&7)*8+d
            #pragma unroll
            for (int d = 0; d < 8; ++d)
                shA[((t & 7) * 8 + d) * 65 + (t >> 3)] = ap[d];
        }
        __syncthreads();
        {
            const int jj = t >> 3, io = (t & 7) * 8;
            float* op = adjT + (size_t)b * 4096 + jj * 64 + io;
            #pragma unroll
            for (int d = 0; d < 8; ++d)
                op[d] = shA[jj * 65 + io + d];
        }
        #pragma unroll 1
        for (int c = 0; c < 8; ++c) {                  // 8 chunks of [8 i][512 jh]
            __syncthreads();
            {
                const float* rp = rel + (size_t)b * 32768 + c * 4096 + t * 8;
                const int i8 = t >> 6;
                const int g  = t & 63;                 // jh = g*8 + d
                #pragma unroll
                for (int d = 0; d < 8; ++d)
                    shR[i8 * 576 + g * 9 + d] = rp[d];
            }
            __syncthreads();
            {
                float* op = relT + (size_t)b * 32768 + (size_t)t * 64 + c * 8;
                const int g = t >> 3, d0 = t & 7;
                #pragma unroll
                for (int i8 = 0; i8 < 8; ++i8)
                    op[i8] = shR[i8 * 576 + g * 9 + d0];
            }
        }
    }
}

// attn: i-ORDER. 256 blocks (1 graph) x 512 threads (j, hh). R[64]/A[64]
// prefetched contiguous to regs; K/V/PE staged to LDS; loop = regs + LDS
// broadcast only, fully unrolled, zero in-loop global memory.
__global__ __launch_bounds__(512, 1) void attn_kernel(
    const float* __restrict__ Qs, const float* __restrict__ Ks,
    const float* __restrict__ Vs, const float* __restrict__ PEs,
    const float* __restrict__ adjT,
    const float* __restrict__ relT,
    float* __restrict__ wVg,          // [16384*64] = h_out region (normalized wV)
    float* __restrict__ scsp)
{
    __shared__ float shK[64 * 64];    // [i][64], plain (broadcast rows)
    __shared__ float shV[64 * 64];
    __shared__ float shPE[1024 * 8];  // proj_e -> sc in place (r7 swap)

    const int b  = blockIdx.x;
    const int t  = threadIdx.x;       // 512 = 64 j x 8 hh
    const int j  = t >> 3;
    const int hh = t & 7;

    // ---- bulk register prefetch: this thread's full rel/adj rows (contiguous)
    const float* rT = relT + (size_t)b * 32768 + (size_t)t * 64;
    const float* aT = adjT + (size_t)b * 4096 + (size_t)j * 64;
    float R[64], A[64];
    #pragma unroll
    for (int u = 0; u < 16; ++u) {
        const float4 x = *(const float4*)(rT + u * 4);
        R[u*4+0] = x.x; R[u*4+1] = x.y; R[u*4+2] = x.z; R[u*4+3] = x.w;
        const float4 y = *(const float4*)(aT + u * 4);
        A[u*4+0] = y.x; A[u*4+1] = y.y; A[u*4+2] = y.z; A[u*4+3] = y.w;
    }
    // ---- stage K, V, PE (coalesced); q per-thread
    {
        const float4* srcK = (const float4*)(Ks + (size_t)b * 4096);
        const float4* srcV = (const float4*)(Vs + (size_t)b * 4096);
        float4* dK = (float4*)shK; float4* dV = (float4*)shV;
        #pragma unroll
        for (int u = 0; u < 2; ++u) {
            dK[u * 512 + t] = srcK[u * 512 + t];
            dV[u * 512 + t] = srcV[u * 512 + t];
        }
        const float4* srcP = (const float4*)(PEs + (size_t)b * 8192);
        float4* dP = (float4*)shPE;
        #pragma unroll
        for (int u = 0; u < 4; ++u)
            dP[u * 512 + t] = srcP[u * 512 + t];
    }
    float q[8];
    {
        const float* qp = Qs + (size_t)(b * 64 + j) * 64 + hh * 8;
        const float4 a = *(const float4*)qp;
        const float4 c4 = *(const float4*)(qp + 4);
        q[0]=a.x; q[1]=a.y; q[2]=a.z; q[3]=a.w;
        q[4]=c4.x; q[5]=c4.y; q[6]=c4.z; q[7]=c4.w;
    }
    __syncthreads();

    // ---- i-loop: wave-uniform i, LDS broadcast K/V, static R/A
    float den = 0.f;
    float wv[8] = {0.f,0.f,0.f,0.f,0.f,0.f,0.f,0.f};
    const float inv_scale = 0.35355339059327379f;  // 1/sqrt(8)
    #pragma unroll
    for (int i = 0; i < 64; ++i) {
        const float4 kA = *(const float4*)&shK[i * 64 + hh * 8];
        const float4 kC = *(const float4*)&shK[i * 64 + hh * 8 + 4];
        float s = kA.x * q[0];
        s = fmaf(kA.y, q[1], s); s = fmaf(kA.z, q[2], s); s = fmaf(kA.w, q[3], s);
        s = fmaf(kC.x, q[4], s); s = fmaf(kC.y, q[5], s); s = fmaf(kC.z, q[6], s);
        s = fmaf(kC.w, q[7], s);
        s = fmaf(s * inv_scale, A[i], R[i]);      // raw score (pre proj_e)
        const int kidx = (i - j - 1) & 63;
        if (kidx < 16) {                          // sparse edge, unique owner
            const int x = (j * 16 + kidx) * 8 + hh;
            const float pe = shPE[x];             // read proj_e once
            shPE[x] = s;                          // overwrite with sc_sp in place
            s += pe;                              // softmax sees sc + proj_e
        }
        s = fminf(fmaxf(s, -5.f), 5.f);
        const float ex = __expf(s);
        den += ex;
        const float4 vA = *(const float4*)&shV[i * 64 + hh * 8];
        const float4 vC = *(const float4*)&shV[i * 64 + hh * 8 + 4];
        wv[0] = fmaf(ex, vA.x, wv[0]); wv[1] = fmaf(ex, vA.y, wv[1]);
        wv[2] = fmaf(ex, vA.z, wv[2]); wv[3] = fmaf(ex, vA.w, wv[3]);
        wv[4] = fmaf(ex, vC.x, wv[4]); wv[5] = fmaf(ex, vC.y, wv[5]);
        wv[6] = fmaf(ex, vC.z, wv[6]); wv[7] = fmaf(ex, vC.w, wv[7]);
    }
    __syncthreads();                 // all PE->SC swaps complete

    // ---- coalesced sc dump + normalized wV out
    {
        const float4* src = (const float4*)shPE;
        float4* dst = (float4*)(scsp + (size_t)b * 8192);
        #pragma unroll
        for (int u = 0; u < 4; ++u)
            dst[u * 512 + t] = src[u * 512 + t];
    }
    const float id = 1.f / den;
    float* wp = wVg + (size_t)(b * 64 + j) * 64 + hh * 8;
    *(float4*)(wp)     = make_float4(wv[0]*id, wv[1]*id, wv[2]*id, wv[3]*id);
    *(float4*)(wp + 4) = make_float4(wv[4]*id, wv[5]*id, wv[6]*id, wv[7]*id);
}

// hout: h_out = wVg @ Wo^T + bo, 4x4 micro-tile; wVg lives IN h_out region
// (tile staged to LDS before overwrite -> safe in-place).
__global__ __launch_bounds__(256, 2) void hout_kernel(
    const float* __restrict__ wVg,
    const float* __restrict__ Wo, const float* __restrict__ bo,
    float* __restrict__ h_out)
{
    __shared__ float shWT[64 * 69];   // [c][r] transposed, stride 69
    __shared__ float shWoT[64 * 65];  // [k][c] = Wo[c][k], stride 65

    const int t    = threadIdx.x;
    const int base = blockIdx.x * 64;

    {
        const int r0 = t >> 2, qq = t & 3;
        const float* ep = wVg + (size_t)(base + r0) * 64 + qq * 16;
        #pragma unroll
        for (int v = 0; v < 4; ++v) {
            const float4 x = ((const float4*)ep)[v];
            const int c = qq * 16 + v * 4;
            shWT[(c + 0) * 69 + r0] = x.x;
            shWT[(c + 1) * 69 + r0] = x.y;
            shWT[(c + 2) * 69 + r0] = x.z;
            shWT[(c + 3) * 69 + r0] = x.w;
        }
    }
    {
        const int c0 = t >> 2, qq = t & 3;
        const float* wp = Wo + c0 * 64 + qq * 16;
        #pragma unroll
        for (int v = 0; v < 4; ++v) {
            const float4 x = ((const float4*)wp)[v];
            const int k = qq * 16 + v * 4;
            shWoT[(k + 0) * 65 + c0] = x.x;
            shWoT[(k + 1) * 65 + c0] = x.y;
            shWoT[(k + 2) * 65 + c0] = x.z;
            shWoT[(k + 3) * 65 + c0] = x.w;
        }
    }
    __syncthreads();

    const int rq = t >> 4;
    const int cq = t & 15;
    float acc[16];
    {
        const float4 bv = *(const float4*)(bo + cq * 4);
        #pragma unroll
        for (int ri = 0; ri < 4; ++ri) {
            acc[ri*4+0] = bv.x; acc[ri*4+1] = bv.y;
            acc[ri*4+2] = bv.z; acc[ri*4+3] = bv.w;
        }
    }
    #pragma unroll
    for (int k = 0; k < 64; ++k) {
        const float4 ev = *(const float4*)&shWT[k * 69 + rq * 4];
        const float4 wk = *(const float4*)&shWoT[k * 65 + cq * 4];
        acc[0]  = fmaf(ev.x, wk.x, acc[0]);  acc[1]  = fmaf(ev.x, wk.y, acc[1]);
        acc[2]  = fmaf(ev.x, wk.z, acc[2]);  acc[3]  = fmaf(ev.x, wk.w, acc[3]);
        acc[4]  = fmaf(ev.y, wk.x, acc[4]);  acc[5]  = fmaf(ev.y, wk.y, acc[5]);
        acc[6]  = fmaf(ev.y, wk.z, acc[6]);  acc[7]  = fmaf(ev.y, wk.w, acc[7]);
        acc[8]  = fmaf(ev.z, wk.x, acc[8]);  acc[9]  = fmaf(ev.z, wk.y, acc[9]);
        acc[10] = fmaf(ev.z, wk.z, acc[10]); acc[11] = fmaf(ev.z, wk.w, acc[11]);
        acc[12] = fmaf(ev.w, wk.x, acc[12]); acc[13] = fmaf(ev.w, wk.y, acc[13]);
        acc[14] = fmaf(ev.w, wk.z, acc[14]); acc[15] = fmaf(ev.w, wk.w, acc[15]);
    }
    #pragma unroll
    for (int ri = 0; ri < 4; ++ri) {
        float* orow = h_out + (size_t)(base + rq * 4 + ri) * 64 + cq * 4;
        *(float4*)orow = make_float4(acc[ri*4+0], acc[ri*4+1], acc[ri*4+2], acc[ri*4+3]);
    }
}

// prep: M2/bc (fallback) + T[73][64] = [Woe^T ; M2^T ; bc].
__global__ void prep_kernel(const float* __restrict__ Wap, const float* __restrict__ bap,
                            const float* __restrict__ Woe, const float* __restrict__ boe,
                            float* __restrict__ M2, float* __restrict__ Tm, int hasT)
{
    const int tg = blockIdx.x * 64 + threadIdx.x;
    if (tg < 512) {
        const int c = tg >> 3, hq = tg & 7;
        float s = 0.f;
        #pragma unroll 8
        for (int k = 0; k < 64; ++k) s = fmaf(Woe[c * 64 + k], Wap[k * 8 + hq], s);
        M2[tg] = s;
    } else if (tg < 576) {
        const int c = tg - 512;
        float s = boe[c];
        #pragma unroll 8
        for (int k = 0; k < 64; ++k) s = fmaf(bap[k], Woe[c * 64 + k], s);
        M2[512 + c] = s;
    } else if (hasT && tg < 576 + 73 * 64) {
        const int idx = tg - 576;
        const int k = idx >> 6, c = idx & 63;
        float v;
        if (k < 64) {
            v = Woe[c * 64 + k];
        } else if (k < 72) {
            const int hq = k - 64;
            v = 0.f;
            #pragma unroll 8
            for (int kk = 0; kk < 64; ++kk)
                v = fmaf(Woe[c * 64 + kk], Wap[kk * 8 + hq], v);
        } else {
            v = boe[c];
            #pragma unroll 8
            for (int kk = 0; kk < 64; ++kk)
                v = fmaf(bap[kk], Woe[c * 64 + kk], v);
        }
        Tm[k * 64 + c] = v;
    }
}

// eoutT: 4x4 micro-tile GEMM (r13/r14 shape). sc folded as k=64..71.
__global__ __launch_bounds__(256, 2) void eoutT_kernel(
    const float* __restrict__ e,
    const float* __restrict__ scsp,
    const float* __restrict__ Tm,      // [73][64]: Woe^T, M2^T, bc
    float* __restrict__ e_out)
{
    __shared__ float shET[72 * 69];   // rows 0..63 e^T, 64..71 sc^T; stride 69
    __shared__ float shTm[73 * 64];   // Tm verbatim (18.7 KB)

    const int t    = threadIdx.x;
    const int base = blockIdx.x * 64;

    {
        const int r0 = t >> 2, qq = t & 3;
        const float* ep = e + (size_t)(base + r0) * 64 + qq * 16;
        #pragma unroll
        for (int v = 0; v < 4; ++v) {
            const float4 x = ((const float4*)ep)[v];
            const int c = qq * 16 + v * 4;
            shET[(c + 0) * 69 + r0] = x.x;
            shET[(c + 1) * 69 + r0] = x.y;
            shET[(c + 2) * 69 + r0] = x.z;
            shET[(c + 3) * 69 + r0] = x.w;
        }
    }
    if (t < 128) {
        const int r = t >> 1, pp = t & 1;
        const float4 s4 = *(const float4*)(scsp + (size_t)(base + r) * 8 + pp * 4);
        shET[(64 + pp * 4 + 0) * 69 + r] = s4.x;
        shET[(64 + pp * 4 + 1) * 69 + r] = s4.y;
        shET[(64 + pp * 4 + 2) * 69 + r] = s4.z;
        shET[(64 + pp * 4 + 3) * 69 + r] = s4.w;
    }
    #pragma unroll
    for (int v = 0; v < 5; ++v) {
        const int fi = v * 256 + t;
        if (fi < 1168)
            *(float4*)&shTm[fi * 4] = *(const float4*)(Tm + fi * 4);
    }
    __syncthreads();

    const int rq = t >> 4;
    const int cq = t & 15;
    float acc[16];
    {
        const float4 bcv = *(const float4*)&shTm[72 * 64 + cq * 4];
        #pragma unroll
        for (int ri = 0; ri < 4; ++ri) {
            acc[ri*4+0] = bcv.x; acc[ri*4+1] = bcv.y;
            acc[ri*4+2] = bcv.z; acc[ri*4+3] = bcv.w;
        }
    }
    #pragma unroll
    for (int k = 0; k < 72; ++k) {
        const float4 ev = *(const float4*)&shET[k * 69 + rq * 4];
        const float4 wk = *(const float4*)&shTm[k * 64 + cq * 4];
        acc[0]  = fmaf(ev.x, wk.x, acc[0]);  acc[1]  = fmaf(ev.x, wk.y, acc[1]);
        acc[2]  = fmaf(ev.x, wk.z, acc[2]);  acc[3]  = fmaf(ev.x, wk.w, acc[3]);
        acc[4]  = fmaf(ev.y, wk.x, acc[4]);  acc[5]  = fmaf(ev.y, wk.y, acc[5]);
        acc[6]  = fmaf(ev.y, wk.z, acc[6]);  acc[7]  = fmaf(ev.y, wk.w, acc[7]);
        acc[8]  = fmaf(ev.z, wk.x, acc[8]);  acc[9]  = fmaf(ev.z, wk.y, acc[9]);
        acc[10] = fmaf(ev.z, wk.z, acc[10]); acc[11] = fmaf(ev.z, wk.w, acc[11]);
        acc[12] = fmaf(ev.w, wk.x, acc[12]); acc[13] = fmaf(ev.w, wk.y, acc[13]);
        acc[14] = fmaf(ev.w, wk.z, acc[14]); acc[15] = fmaf(ev.w, wk.w, acc[15]);
    }
    #pragma unroll
    for (int ri = 0; ri < 4; ++ri) {
        float* orow = e_out + (size_t)(base + rq * 4 + ri) * 64 + cq * 4;
        *(float4*)orow = make_float4(acc[ri*4+0], acc[ri*4+1], acc[ri*4+2], acc[ri*4+3]);
    }
}

// Fallback eout if d_ws can't hold Tm.
__global__ __launch_bounds__(256, 2) void eout_kernel(
    const float* __restrict__ e,
    const float* __restrict__ scsp,
    const float* __restrict__ Woe,
    const float* __restrict__ M2g,
    float* __restrict__ e_out)
{
    __shared__ float shE[64 * 64];
    __shared__ float shS[64 * 8];
    const int t    = threadIdx.x;
    const int base = blockIdx.x * 64;
    {
        const int r = t >> 2, qq = t & 3;
        const float* ep = e + (size_t)(base + r) * 64 + qq * 16;
        #pragma unroll
        for (int u = 0; u < 4; ++u) {
            const float4 x = ((const float4*)ep)[u];
            const int cc = qq * 4 + u;
            *(float4*)&shE[r * 64 + ((cc ^ (r & 15)) << 2)] = x;
        }
    }
    if (t < 128) {
        const int r = t >> 1, pp = t & 1;
        *(float4*)&shS[r * 8 + pp * 4] =
            *(const float4*)(scsp + (size_t)(base + r) * 8 + pp * 4);
    }
    __syncthreads();
    const int w = __builtin_amdgcn_readfirstlane(t >> 6);
    const int r = t & 63;
    float sc[8];
    {
        const float4 a  = *(const float4*)&shS[r * 8];
        const float4 c4 = *(const float4*)&shS[r * 8 + 4];
        sc[0]=a.x; sc[1]=a.y; sc[2]=a.z; sc[3]=a.w;
        sc[4]=c4.x; sc[5]=c4.y; sc[6]=c4.z; sc[7]=c4.w;
    }
    float acc[16];
    #pragma unroll
    for (int u = 0; u < 16; ++u) {
        const int c = w * 16 + u;
        float s = M2g[512 + c];
        #pragma unroll
        for (int hq = 0; hq < 8; ++hq)
            s = fmaf(sc[hq], M2g[c * 8 + hq], s);
        acc[u] = s;
    }
    #pragma unroll
    for (int k0 = 0; k0 < 4; ++k0) {
        float ev[16];
        #pragma unroll
        for (int v = 0; v < 4; ++v) {
            const int cc = k0 * 4 + v;
            const float4 x = *(const float4*)&shE[r * 64 + ((cc ^ (r & 15)) << 2)];
            ev[v*4+0] = x.x; ev[v*4+1] = x.y; ev[v*4+2] = x.z; ev[v*4+3] = x.w;
        }
        #pragma unroll
        for (int u = 0; u < 16; ++u) {
            const float* wr = Woe + (w * 16 + u) * 64 + k0 * 16;
            #pragma unroll
            for (int k = 0; k < 16; ++k)
                acc[u] = fmaf(ev[k], wr[k], acc[u]);
        }
    }
    float* orow = e_out + (size_t)(base + r) * 64 + w * 16;
    #pragma unroll
    for (int u = 0; u < 4; ++u)
        *(float4*)&orow[u * 4] =
            make_float4(acc[u*4+0], acc[u*4+1], acc[u*4+2], acc[u*4+3]);
}

extern "C" void kernel_launch(void* const* d_in, const int* in_sizes, int n_in,
                              void* d_out, int out_size, void* d_ws, size_t ws_size,
                              hipStream_t stream) {
    const float* h    = (const float*)d_in[0];
    const float* e    = (const float*)d_in[1];
    const float* adj2 = (const float*)d_in[2];
    const float* rel  = (const float*)d_in[3];
    const float* Wq   = (const float*)d_in[4];  const float* bq  = (const float*)d_in[5];
    const float* Wk   = (const float*)d_in[6];  const float* bk  = (const float*)d_in[7];
    const float* Wv   = (const float*)d_in[8];  const float* bv  = (const float*)d_in[9];
    const float* Wpe  = (const float*)d_in[10]; const float* bpe = (const float*)d_in[11];
    const float* Wap  = (const float*)d_in[12]; const float* bap = (const float*)d_in[13];
    const float* Wo   = (const float*)d_in[14]; const float* bo  = (const float*)d_in[15];
    const float* Woe  = (const float*)d_in[16]; const float* boe = (const float*)d_in[17];

    float* out  = (float*)d_out;
    float* hout = out;                        // [16384*64]; holds wVg between kernels
    float* eout = out + 16384 * 64;           // [262144*64], staging (dead at eout time)
    float* Qs   = eout;
    float* Ks   = eout + 1048576;
    float* Vs   = eout + 2097152;
    float* PEs  = eout + 3145728;             // ends 5242880
    float* relT = eout + 5242880;             // [256][512][64] -> ends 13631488
    float* adjT = eout + 13631488;            // [256][64][64]  -> ends 14680064
    float* ws   = (float*)d_ws;
    float* scsp = ws;                         // [262144*8]
    float* M2g  = ws + 2097152;               // [576]
    float* Tm   = ws + 2098176;               // [73*64]
    const int hasT = (ws_size >= (size_t)(2098176 + 73 * 64) * sizeof(float)) ? 1 : 0;

    prep_kernel<<<dim3(82), dim3(64), 0, stream>>>(Wap, bap, Woe, boe, M2g, Tm, hasT);
    qkvpe_kernel<<<dim3(1024), dim3(512), 0, stream>>>(
        h, e, adj2, rel, Wq, bq, Wk, bk, Wv, bv, Wpe, bpe,
        Qs, Ks, Vs, PEs, relT, adjT);
    attn_kernel<<<dim3(256), dim3(512), 0, stream>>>(
        Qs, Ks, Vs, PEs, adjT, relT, hout /*wVg*/, scsp);
    hout_kernel<<<dim3(256), dim3(256), 0, stream>>>(hout, Wo, bo, hout);
    if (hasT)
        eoutT_kernel<<<dim3(4096), dim3(256), 0, stream>>>(e, scsp, Tm, eout);
    else
        eout_kernel<<<dim3(4096), dim3(256), 0, stream>>>(e, scsp, Woe, M2g, eout);
}

// Round 16
// 163.771 us; speedup vs baseline: 1.3631x; 1.3631x over previous
//
#include <hip/hip_runtime.h>

// Geometry: G=256 graphs x 64 nodes, H=8 heads x D=8, IN_DIM=EDGE_DIM=64
// EF = 1048576 full edges, ES = 262144 sparse edges.
// edge f = b*4096 + i*64 + j (src=i, dst=j); sparse s = b*1024 + j*16 + k, i=(j+1+k)&63.
//
// Staging (floats, in d_out's eout region, dead before eoutT writes):
//   Qs @0, Ks @1048576, Vs @2097152, PEs @3145728,
//   relT2 @5242880 [b][c=i/8][jh][i%8] (8.4M), adjT2 @13631488 [b][c][j][i%8] (1M).
//   d_ws: scsp [262144*8] @0, M2 [576] @2097152, Tm [73*64] @2098176.
// NOTE VGPR cap = 131072/(threads*minwaves); exceeding -> spill (WRITE_SIZE alarm).
// NOTE r15 meta-result: the ~60us attn wall = ISSUE PATTERN. Loads interleaved
// with dependent compute idle the machine (~750GB/s); bulk-issued wide loads
// stream at 2.9TB/s even at 0.1% occupancy. Bulk-prefetch into registers, but
// keep demand under the cap (r15 spilled at demand~170/cap128: 330MB traffic).
// NOTE eoutT was LDS-issue-bound (2 b128/16 FMA); 8x8 tile = 4 b128/64 FMA.

// qkv (blocks 0..255) + pe (256..767) + rel/adj transpose (768..1023).
__global__ __launch_bounds__(512, 2) void qkvpe_kernel(
    const float* __restrict__ h,
    const float* __restrict__ e,
    const float* __restrict__ adj2,
    const float* __restrict__ rel,
    const float* __restrict__ Wq, const float* __restrict__ bq,
    const float* __restrict__ Wk, const float* __restrict__ bk,
    const float* __restrict__ Wv, const float* __restrict__ bv,
    const float* __restrict__ Wpe, const float* __restrict__ bpe,
    float* __restrict__ Qs, float* __restrict__ Ks, float* __restrict__ Vs,
    float* __restrict__ PEs, float* __restrict__ relT, float* __restrict__ adjT)
{
    __shared__ float shA[64 * 65];   // adj transpose tile [j][i]
    __shared__ float shR[8 * 576];   // rel transpose tile [i8][(jh/8)*9 + jh%8]
    const int t = threadIdx.x;
    if (blockIdx.x < 256) {
        const int b    = blockIdx.x;
        const int lane = t & 63;
        const int wu   = __builtin_amdgcn_readfirstlane(t >> 6);   // 8 cols per wave
        const float* hrow = h + (size_t)(b * 64 + lane) * 64;
        float accQ[8], accK[8], accV[8];
        #pragma unroll
        for (int cc = 0; cc < 8; ++cc) {
            const int c = wu * 8 + cc;
            accQ[cc] = bq[c]; accK[cc] = bk[c]; accV[cc] = bv[c];
        }
        #pragma unroll 1
        for (int k0 = 0; k0 < 4; ++k0) {
            float hv[16];
            #pragma unroll
            for (int u = 0; u < 4; ++u) {
                const float4 x = ((const float4*)hrow)[k0 * 4 + u];
                hv[u*4+0] = x.x; hv[u*4+1] = x.y; hv[u*4+2] = x.z; hv[u*4+3] = x.w;
            }
            #pragma unroll
            for (int cc = 0; cc < 8; ++cc) {
                const int c = wu * 8 + cc;
                const float* wq  = Wq + c * 64 + k0 * 16;   // wave-uniform -> s_load
                const float* wk  = Wk + c * 64 + k0 * 16;
                const float* wvp = Wv + c * 64 + k0 * 16;
                #pragma unroll
                for (int k = 0; k < 16; ++k) {
                    accQ[cc] = fmaf(hv[k], wq[k],  accQ[cc]);
                    accK[cc] = fmaf(hv[k], wk[k],  accK[cc]);
                    accV[cc] = fmaf(hv[k], wvp[k], accV[cc]);
                }
            }
        }
        const size_t o = (size_t)(b * 64 + lane) * 64 + wu * 8;
        *(float4*)(Qs + o)     = make_float4(accQ[0], accQ[1], accQ[2], accQ[3]);
        *(float4*)(Qs + o + 4) = make_float4(accQ[4], accQ[5], accQ[6], accQ[7]);
        *(float4*)(Ks + o)     = make_float4(accK[0], accK[1], accK[2], accK[3]);
        *(float4*)(Ks + o + 4) = make_float4(accK[4], accK[5], accK[6], accK[7]);
        *(float4*)(Vs + o)     = make_float4(accV[0], accV[1], accV[2], accV[3]);
        *(float4*)(Vs + o + 4) = make_float4(accV[4], accV[5], accV[6], accV[7]);
    } else if (blockIdx.x < 768) {
        const int row = (blockIdx.x - 256) * 512 + t;      // 0..ES-1
        const float* erow = e + (size_t)row * 64;
        float acc[8];
        #pragma unroll
        for (int h2 = 0; h2 < 8; ++h2) acc[h2] = bpe[h2];
        #pragma unroll 1
        for (int k0 = 0; k0 < 4; ++k0) {
            float ev[16];
            #pragma unroll
            for (int u = 0; u < 4; ++u) {
                const float4 x = ((const float4*)erow)[k0 * 4 + u];
                ev[u*4+0] = x.x; ev[u*4+1] = x.y; ev[u*4+2] = x.z; ev[u*4+3] = x.w;
            }
            #pragma unroll
            for (int h2 = 0; h2 < 8; ++h2) {
                const float* wp = Wpe + h2 * 64 + k0 * 16;  // uniform -> s_load
                #pragma unroll
                for (int k = 0; k < 16; ++k)
                    acc[h2] = fmaf(ev[k], wp[k], acc[h2]);
            }
        }
        float* p0 = PEs + (size_t)row * 8;
        *(float4*)(p0)     = make_float4(acc[0], acc[1], acc[2], acc[3]);
        *(float4*)(p0 + 4) = make_float4(acc[4], acc[5], acc[6], acc[7]);
    } else {
        const int b = blockIdx.x - 768;
        // adj [i][j] -> adjT2 [c][j][d] (d = i%8, c = i/8)
        {
            const float* ap = adj2 + (size_t)b * 4096 + t * 8;   // i=t>>3, j0=(t&7)*8
            #pragma unroll
            for (int d = 0; d < 8; ++d)
                shA[((t & 7) * 8 + d) * 65 + (t >> 3)] = ap[d];
        }
        __syncthreads();
        {
            const int j = t & 63, c = t >> 6;                    // c 0..7
            float* op = adjT + (size_t)b * 4096 + c * 512 + j * 8;
            #pragma unroll
            for (int d = 0; d < 8; ++d)
                op[d] = shA[j * 65 + c * 8 + d];
        }
        // rel [i][jh] -> relT2 [c][jh][d], 8 chunks of 8 i-rows
        #pragma unroll 1
        for (int c = 0; c < 8; ++c) {
            __syncthreads();
            {
                const float* rp = rel + (size_t)b * 32768 + c * 4096 + t * 8;
                const int i8 = t >> 6;
                const int g  = t & 63;                 // jh = g*8 + d
                #pragma unroll
                for (int d = 0; d < 8; ++d)
                    shR[i8 * 576 + g * 9 + d] = rp[d];
            }
            __syncthreads();
            {
                float* op = relT + (size_t)b * 32768 + c * 4096 + t * 8;  // jh = t
                #pragma unroll
                for (int i8 = 0; i8 < 8; ++i8)
                    op[i8] = shR[i8 * 576 + (t >> 3) * 9 + (t & 7)];
            }
        }
    }
}

// attn: 512 blocks = (b, jhalf), 256 threads = (jl = t>>3, hh = t&7).
// R[64] rel prefetched in one contiguous burst (16 float4, wave = 2KB runs);
// adj/K/V/PE in LDS; loop fully unrolled, zero in-loop global memory;
// full 64-i per thread -> NO reductions. VGPR ~115 < 128 cap, no spill.
__global__ __launch_bounds__(256, 1) void attn_kernel(
    const float* __restrict__ Qs, const float* __restrict__ Ks,
    const float* __restrict__ Vs, const float* __restrict__ PEs,
    const float* __restrict__ adjT,
    const float* __restrict__ relT,
    float* __restrict__ wVg,          // [16384*64] = h_out region (normalized wV)
    float* __restrict__ scsp)
{
    __shared__ float shK[64 * 64];    // [i][dim], plain (broadcast rows)
    __shared__ float shV[64 * 64];
    __shared__ float shPE[512 * 8];   // this j-half's proj_e -> sc in place
    __shared__ float shAdj[64 * 33];  // [i][jl]

    const int b2 = blockIdx.x;
    const int b  = b2 >> 1;
    const int j0 = (b2 & 1) << 5;
    const int t  = threadIdx.x;
    const int jl = t >> 3;
    const int hh = t & 7;
    const int j  = j0 + jl;

    // ---- bulk register prefetch: R[64] (this thread's rel row, chunk layout)
    const float* rT = relT + (size_t)b * 32768 + (size_t)j0 * 64 + t * 8;
    float R[64];
    #pragma unroll
    for (int c = 0; c < 8; ++c) {
        const float4 x = *(const float4*)(rT + c * 4096);
        const float4 y = *(const float4*)(rT + c * 4096 + 4);
        R[c*8+0] = x.x; R[c*8+1] = x.y; R[c*8+2] = x.z; R[c*8+3] = x.w;
        R[c*8+4] = y.x; R[c*8+5] = y.y; R[c*8+6] = y.z; R[c*8+7] = y.w;
    }
    // ---- stage K, V, PE slice, adj (coalesced); q per-thread
    {
        const float4* srcK = (const float4*)(Ks + (size_t)b * 4096);
        const float4* srcV = (const float4*)(Vs + (size_t)b * 4096);
        float4* dK = (float4*)shK; float4* dV = (float4*)shV;
        #pragma unroll
        for (int u = 0; u < 4; ++u) {
            dK[u * 256 + t] = srcK[u * 256 + t];
            dV[u * 256 + t] = srcV[u * 256 + t];
        }
        const float4* srcP = (const float4*)(PEs + ((size_t)b * 1024 + j0 * 16) * 8);
        float4* dP = (float4*)shPE;
        #pragma unroll
        for (int u = 0; u < 4; ++u)
            dP[u * 256 + t] = srcP[u * 256 + t];
    }
    {   // adj: thread t -> chunk c = t>>5, j = j0 + (t&31); 8 d-values
        const int c = t >> 5, o = t & 31;
        const float4 a0 = *(const float4*)(adjT + (size_t)b * 4096 + c * 512 + (j0 + o) * 8);
        const float4 a1 = *(const float4*)(adjT + (size_t)b * 4096 + c * 512 + (j0 + o) * 8 + 4);
        shAdj[(c*8+0) * 33 + o] = a0.x; shAdj[(c*8+1) * 33 + o] = a0.y;
        shAdj[(c*8+2) * 33 + o] = a0.z; shAdj[(c*8+3) * 33 + o] = a0.w;
        shAdj[(c*8+4) * 33 + o] = a1.x; shAdj[(c*8+5) * 33 + o] = a1.y;
        shAdj[(c*8+6) * 33 + o] = a1.z; shAdj[(c*8+7) * 33 + o] = a1.w;
    }
    float q[8];
    {
        const float* qp = Qs + (size_t)(b * 64 + j) * 64 + hh * 8;
        const float4 a = *(const float4*)qp;
        const float4 c4 = *(const float4*)(qp + 4);
        q[0]=a.x; q[1]=a.y; q[2]=a.z; q[3]=a.w;
        q[4]=c4.x; q[5]=c4.y; q[6]=c4.z; q[7]=c4.w;
    }
    __syncthreads();

    // ---- i-loop: pure regs + LDS broadcast, fully unrolled (R[i] static)
    float den = 0.f;
    float wv[8] = {0.f,0.f,0.f,0.f,0.f,0.f,0.f,0.f};
    const float inv_scale = 0.35355339059327379f;  // 1/sqrt(8)
    #pragma unroll
    for (int i = 0; i < 64; ++i) {
        const float4 kA = *(const float4*)&shK[i * 64 + hh * 8];
        const float4 kC = *(const float4*)&shK[i * 64 + hh * 8 + 4];
        float s = kA.x * q[0];
        s = fmaf(kA.y, q[1], s); s = fmaf(kA.z, q[2], s); s = fmaf(kA.w, q[3], s);
        s = fmaf(kC.x, q[4], s); s = fmaf(kC.y, q[5], s); s = fmaf(kC.z, q[6], s);
        s = fmaf(kC.w, q[7], s);
        s = fmaf(s * inv_scale, shAdj[i * 33 + jl], R[i]);   // raw score
        const int kidx = (i - j - 1) & 63;
        if (kidx < 16) {                          // sparse edge, unique owner
            const int x = (jl * 16 + kidx) * 8 + hh;
            const float pe = shPE[x];             // read proj_e once
            shPE[x] = s;                          // overwrite with sc_sp in place
            s += pe;                              // softmax sees sc + proj_e
        }
        s = fminf(fmaxf(s, -5.f), 5.f);
        const float ex = __expf(s);
        den += ex;
        const float4 vA = *(const float4*)&shV[i * 64 + hh * 8];
        const float4 vC = *(const float4*)&shV[i * 64 + hh * 8 + 4];
        wv[0] = fmaf(ex, vA.x, wv[0]); wv[1] = fmaf(ex, vA.y, wv[1]);
        wv[2] = fmaf(ex, vA.z, wv[2]); wv[3] = fmaf(ex, vA.w, wv[3]);
        wv[4] = fmaf(ex, vC.x, wv[4]); wv[5] = fmaf(ex, vC.y, wv[5]);
        wv[6] = fmaf(ex, vC.z, wv[6]); wv[7] = fmaf(ex, vC.w, wv[7]);
    }
    __syncthreads();                 // all PE->SC swaps complete

    // ---- coalesced sc dump + normalized wV out
    {
        const float4* src = (const float4*)shPE;
        float4* dst = (float4*)(scsp + ((size_t)b * 1024 + j0 * 16) * 8);
        #pragma unroll
        for (int u = 0; u < 4; ++u)
            dst[u * 256 + t] = src[u * 256 + t];
    }
    const float id = 1.f / den;
    float* wp = wVg + (size_t)(b * 64 + j) * 64 + hh * 8;
    *(float4*)(wp)     = make_float4(wv[0]*id, wv[1]*id, wv[2]*id, wv[3]*id);
    *(float4*)(wp + 4) = make_float4(wv[4]*id, wv[5]*id, wv[6]*id, wv[7]*id);
}

// hout: h_out = wVg @ Wo^T + bo, 4x4 micro-tile; wVg lives IN h_out region.
__global__ __launch_bounds__(256, 2) void hout_kernel(
    const float* __restrict__ wVg,
    const float* __restrict__ Wo, const float* __restrict__ bo,
    float* __restrict__ h_out)
{
    __shared__ float shWT[64 * 69];
    __shared__ float shWoT[64 * 65];

    const int t    = threadIdx.x;
    const int base = blockIdx.x * 64;
    {
        const int r0 = t >> 2, qq = t & 3;
        const float* ep = wVg + (size_t)(base + r0) * 64 + qq * 16;
        #pragma unroll
        for (int v = 0; v < 4; ++v) {
            const float4 x = ((const float4*)ep)[v];
            const int c = qq * 16 + v * 4;
            shWT[(c + 0) * 69 + r0] = x.x;
            shWT[(c + 1) * 69 + r0] = x.y;
            shWT[(c + 2) * 69 + r0] = x.z;
            shWT[(c + 3) * 69 + r0] = x.w;
        }
    }
    {
        const int c0 = t >> 2, qq = t & 3;
        const float* wp = Wo + c0 * 64 + qq * 16;
        #pragma unroll
        for (int v = 0; v < 4; ++v) {
            const float4 x = ((const float4*)wp)[v];
            const int k = qq * 16 + v * 4;
            shWoT[(k + 0) * 65 + c0] = x.x;
            shWoT[(k + 1) * 65 + c0] = x.y;
            shWoT[(k + 2) * 65 + c0] = x.z;
            shWoT[(k + 3) * 65 + c0] = x.w;
        }
    }
    __syncthreads();

    const int rq = t >> 4, cq = t & 15;
    float acc[16];
    {
        const float4 bv = *(const float4*)(bo + cq * 4);
        #pragma unroll
        for (int ri = 0; ri < 4; ++ri) {
            acc[ri*4+0] = bv.x; acc[ri*4+1] = bv.y;
            acc[ri*4+2] = bv.z; acc[ri*4+3] = bv.w;
        }
    }
    #pragma unroll
    for (int k = 0; k < 64; ++k) {
        const float4 ev = *(const float4*)&shWT[k * 69 + rq * 4];
        const float4 wk = *(const float4*)&shWoT[k * 65 + cq * 4];
        acc[0]  = fmaf(ev.x, wk.x, acc[0]);  acc[1]  = fmaf(ev.x, wk.y, acc[1]);
        acc[2]  = fmaf(ev.x, wk.z, acc[2]);  acc[3]  = fmaf(ev.x, wk.w, acc[3]);
        acc[4]  = fmaf(ev.y, wk.x, acc[4]);  acc[5]  = fmaf(ev.y, wk.y, acc[5]);
        acc[6]  = fmaf(ev.y, wk.z, acc[6]);  acc[7]  = fmaf(ev.y, wk.w, acc[7]);
        acc[8]  = fmaf(ev.z, wk.x, acc[8]);  acc[9]  = fmaf(ev.z, wk.y, acc[9]);
        acc[10] = fmaf(ev.z, wk.z, acc[10]); acc[11] = fmaf(ev.z, wk.w, acc[11]);
        acc[12] = fmaf(ev.w, wk.x, acc[12]); acc[13] = fmaf(ev.w, wk.y, acc[13]);
        acc[14] = fmaf(ev.w, wk.z, acc[14]); acc[15] = fmaf(ev.w, wk.w, acc[15]);
    }
    #pragma unroll
    for (int ri = 0; ri < 4; ++ri) {
        float* orow = h_out + (size_t)(base + rq * 4 + ri) * 64 + cq * 4;
        *(float4*)orow = make_float4(acc[ri*4+0], acc[ri*4+1], acc[ri*4+2], acc[ri*4+3]);
    }
}

// prep: M2/bc (fallback) + T[73][64] = [Woe^T ; M2^T ; bc].
__global__ void prep_kernel(const float* __restrict__ Wap, const float* __restrict__ bap,
                            const float* __restrict__ Woe, const float* __restrict__ boe,
                            float* __restrict__ M2, float* __restrict__ Tm, int hasT)
{
    const int tg = blockIdx.x * 64 + threadIdx.x;
    if (tg < 512) {
        const int c = tg >> 3, hq = tg & 7;
        float s = 0.f;
        #pragma unroll 8
        for (int k = 0; k < 64; ++k) s = fmaf(Woe[c * 64 + k], Wap[k * 8 + hq], s);
        M2[tg] = s;
    } else if (tg < 576) {
        const int c = tg - 512;
        float s = boe[c];
        #pragma unroll 8
        for (int k = 0; k < 64; ++k) s = fmaf(bap[k], Woe[c * 64 + k], s);
        M2[512 + c] = s;
    } else if (hasT && tg < 576 + 73 * 64) {
        const int idx = tg - 576;
        const int k = idx >> 6, c = idx & 63;
        float v;
        if (k < 64) {
            v = Woe[c * 64 + k];
        } else if (k < 72) {
            const int hq = k - 64;
            v = 0.f;
            #pragma unroll 8
            for (int kk = 0; kk < 64; ++kk)
                v = fmaf(Woe[c * 64 + kk], Wap[kk * 8 + hq], v);
        } else {
            v = boe[c];
            #pragma unroll 8
            for (int kk = 0; kk < 64; ++kk)
                v = fmaf(bap[kk], Woe[c * 64 + kk], v);
        }
        Tm[k * 64 + c] = v;
    }
}

// eoutT: 8x8 micro-tile, 64-thread blocks. Per k: 4 b128 LDS reads feed 64
// independent FMAs (LDS pipe no longer the bottleneck). sc folded as k=64..71.
__global__ __launch_bounds__(64, 1) void eoutT_kernel(
    const float* __restrict__ e,
    const float* __restrict__ scsp,
    const float* __restrict__ Tm,      // [73][64]: Woe^T, M2^T, bc
    float* __restrict__ e_out)
{
    __shared__ float shET[72 * 72];   // [k][r], stride 72 (16B-aligned rows)
    __shared__ float shTm[73 * 64];

    const int t    = threadIdx.x;     // 0..63
    const int base = blockIdx.x * 64;

    {   // thread t owns global row base+t: read 64 floats, write column t
        const float* ep = e + (size_t)(base + t) * 64;
        #pragma unroll
        for (int v = 0; v < 16; ++v) {
            const float4 x = ((const float4*)ep)[v];
            shET[(v*4+0) * 72 + t] = x.x;
            shET[(v*4+1) * 72 + t] = x.y;
            shET[(v*4+2) * 72 + t] = x.z;
            shET[(v*4+3) * 72 + t] = x.w;
        }
        const float4 s0 = *(const float4*)(scsp + (size_t)(base + t) * 8);
        const float4 s1 = *(const float4*)(scsp + (size_t)(base + t) * 8 + 4);
        shET[(64+0) * 72 + t] = s0.x; shET[(64+1) * 72 + t] = s0.y;
        shET[(64+2) * 72 + t] = s0.z; shET[(64+3) * 72 + t] = s0.w;
        shET[(64+4) * 72 + t] = s1.x; shET[(64+5) * 72 + t] = s1.y;
        shET[(64+6) * 72 + t] = s1.z; shET[(64+7) * 72 + t] = s1.w;
    }
    #pragma unroll
    for (int v = 0; v < 19; ++v) {    // stage Tm: 1168 float4 / 64 threads
        const int fi = v * 64 + t;
        if (fi < 1168)
            *(float4*)&shTm[fi * 4] = *(const float4*)(Tm + fi * 4);
    }
    __syncthreads();

    const int rq = t >> 3;            // row oct 0..7
    const int cq = t & 7;             // col oct 0..7
    float acc[64];
    {
        const float4 b0 = *(const float4*)&shTm[72 * 64 + cq * 8];
        const float4 b1 = *(const float4*)&shTm[72 * 64 + cq * 8 + 4];
        #pragma unroll
        for (int ri = 0; ri < 8; ++ri) {
            acc[ri*8+0] = b0.x; acc[ri*8+1] = b0.y; acc[ri*8+2] = b0.z; acc[ri*8+3] = b0.w;
            acc[ri*8+4] = b1.x; acc[ri*8+5] = b1.y; acc[ri*8+6] = b1.z; acc[ri*8+7] = b1.w;
        }
    }
    #pragma unroll 4
    for (int k = 0; k < 72; ++k) {
        float ev[8], wk[8];
        {
            const float4 e0 = *(const float4*)&shET[k * 72 + rq * 8];
            const float4 e1 = *(const float4*)&shET[k * 72 + rq * 8 + 4];
            ev[0]=e0.x; ev[1]=e0.y; ev[2]=e0.z; ev[3]=e0.w;
            ev[4]=e1.x; ev[5]=e1.y; ev[6]=e1.z; ev[7]=e1.w;
            const float4 w0 = *(const float4*)&shTm[k * 64 + cq * 8];
            const float4 w1 = *(const float4*)&shTm[k * 64 + cq * 8 + 4];
            wk[0]=w0.x; wk[1]=w0.y; wk[2]=w0.z; wk[3]=w0.w;
            wk[4]=w1.x; wk[5]=w1.y; wk[6]=w1.z; wk[7]=w1.w;
        }
        #pragma unroll
        for (int ri = 0; ri < 8; ++ri)
            #pragma unroll
            for (int ci = 0; ci < 8; ++ci)
                acc[ri*8+ci] = fmaf(ev[ri], wk[ci], acc[ri*8+ci]);
    }
    #pragma unroll
    for (int ri = 0; ri < 8; ++ri) {
        float* orow = e_out + (size_t)(base + rq * 8 + ri) * 64 + cq * 8;
        *(float4*)(orow)     = make_float4(acc[ri*8+0], acc[ri*8+1], acc[ri*8+2], acc[ri*8+3]);
        *(float4*)(orow + 4) = make_float4(acc[ri*8+4], acc[ri*8+5], acc[ri*8+6], acc[ri*8+7]);
    }
}

// Fallback eout if d_ws can't hold Tm (r10 shape).
__global__ __launch_bounds__(256, 2) void eout_kernel(
    const float* __restrict__ e,
    const float* __restrict__ scsp,
    const float* __restrict__ Woe,
    const float* __restrict__ M2g,
    float* __restrict__ e_out)
{
    __shared__ float shE[64 * 64];
    __shared__ float shS[64 * 8];
    const int t    = threadIdx.x;
    const int base = blockIdx.x * 64;
    {
        const int r = t >> 2, qq = t & 3;
        const float* ep = e + (size_t)(base + r) * 64 + qq * 16;
        #pragma unroll
        for (int u = 0; u < 4; ++u) {
            const float4 x = ((const float4*)ep)[u];
            const int cc = qq * 4 + u;
            *(float4*)&shE[r * 64 + ((cc ^ (r & 15)) << 2)] = x;
        }
    }
    if (t < 128) {
        const int r = t >> 1, pp = t & 1;
        *(float4*)&shS[r * 8 + pp * 4] =
            *(const float4*)(scsp + (size_t)(base + r) * 8 + pp * 4);
    }
    __syncthreads();
    const int w = __builtin_amdgcn_readfirstlane(t >> 6);
    const int r = t & 63;
    float sc[8];
    {
        const float4 a  = *(const float4*)&shS[r * 8];
        const float4 c4 = *(const float4*)&shS[r * 8 + 4];
        sc[0]=a.x; sc[1]=a.y; sc[2]=a.z; sc[3]=a.w;
        sc[4]=c4.x; sc[5]=c4.y; sc[6]=c4.z; sc[7]=c4.w;
    }
    float acc[16];
    #pragma unroll
    for (int u = 0; u < 16; ++u) {
        const int c = w * 16 + u;
        float s = M2g[512 + c];
        #pragma unroll
        for (int hq = 0; hq < 8; ++hq)
            s = fmaf(sc[hq], M2g[c * 8 + hq], s);
        acc[u] = s;
    }
    #pragma unroll
    for (int k0 = 0; k0 < 4; ++k0) {
        float ev[16];
        #pragma unroll
        for (int v = 0; v < 4; ++v) {
            const int cc = k0 * 4 + v;
            const float4 x = *(const float4*)&shE[r * 64 + ((cc ^ (r & 15)) << 2)];
            ev[v*4+0] = x.x; ev[v*4+1] = x.y; ev[v*4+2] = x.z; ev[v*4+3] = x.w;
        }
        #pragma unroll
        for (int u = 0; u < 16; ++u) {
            const float* wr = Woe + (w * 16 + u) * 64 + k0 * 16;
            #pragma unroll
            for (int k = 0; k < 16; ++k)
                acc[u] = fmaf(ev[k], wr[k], acc[u]);
        }
    }
    float* orow = e_out + (size_t)(base + r) * 64 + w * 16;
    #pragma unroll
    for (int u = 0; u < 4; ++u)
        *(float4*)&orow[u * 4] =
            make_float4(acc[u*4+0], acc[u*4+1], acc[u*4+2], acc[u*4+3]);
}

extern "C" void kernel_launch(void* const* d_in, const int* in_sizes, int n_in,
                              void* d_out, int out_size, void* d_ws, size_t ws_size,
                              hipStream_t stream) {
    const float* h    = (const float*)d_in[0];
    const float* e    = (const float*)d_in[1];
    const float* adj2 = (const float*)d_in[2];
    const float* rel  = (const float*)d_in[3];
    const float* Wq   = (const float*)d_in[4];  const float* bq  = (const float*)d_in[5];
    const float* Wk   = (const float*)d_in[6];  const float* bk  = (const float*)d_in[7];
    const float* Wv   = (const float*)d_in[8];  const float* bv  = (const float*)d_in[9];
    const float* Wpe  = (const float*)d_in[10]; const float* bpe = (const float*)d_in[11];
    const float* Wap  = (const float*)d_in[12]; const float* bap = (const float*)d_in[13];
    const float* Wo   = (const float*)d_in[14]; const float* bo  = (const float*)d_in[15];
    const float* Woe  = (const float*)d_in[16]; const float* boe = (const float*)d_in[17];

    float* out  = (float*)d_out;
    float* hout = out;                        // [16384*64]; holds wVg between kernels
    float* eout = out + 16384 * 64;           // [262144*64], staging (dead at eout time)
    float* Qs   = eout;
    float* Ks   = eout + 1048576;
    float* Vs   = eout + 2097152;
    float* PEs  = eout + 3145728;             // ends 5242880
    float* relT = eout + 5242880;             // chunked [b][c][jh][d] -> ends 13631488
    float* adjT = eout + 13631488;            // chunked [b][c][j][d]  -> ends 14680064
    float* ws   = (float*)d_ws;
    float* scsp = ws;                         // [262144*8]
    float* M2g  = ws + 2097152;               // [576]
    float* Tm   = ws + 2098176;               // [73*64]
    const int hasT = (ws_size >= (size_t)(2098176 + 73 * 64) * sizeof(float)) ? 1 : 0;

    prep_kernel<<<dim3(82), dim3(64), 0, stream>>>(Wap, bap, Woe, boe, M2g, Tm, hasT);
    qkvpe_kernel<<<dim3(1024), dim3(512), 0, stream>>>(
        h, e, adj2, rel, Wq, bq, Wk, bk, Wv, bv, Wpe, bpe,
        Qs, Ks, Vs, PEs, relT, adjT);
    attn_kernel<<<dim3(512), dim3(256), 0, stream>>>(
        Qs, Ks, Vs, PEs, adjT, relT, hout /*wVg*/, scsp);
    hout_kernel<<<dim3(256), dim3(256), 0, stream>>>(hout, Wo, bo, hout);
    if (hasT)
        eoutT_kernel<<<dim3(4096), dim3(64), 0, stream>>>(e, scsp, Tm, eout);
    else
        eout_kernel<<<dim3(4096), dim3(256), 0, stream>>>(e, scsp, Woe, M2g, eout);
}

// Round 17
// 145.659 us; speedup vs baseline: 1.5326x; 1.1243x over previous
//
#include <hip/hip_runtime.h>

// Geometry: G=256 graphs x 64 nodes, H=8 heads x D=8, IN_DIM=EDGE_DIM=64
// EF = 1048576 full edges, ES = 262144 sparse edges.
// edge f = b*4096 + i*64 + j (src=i, dst=j); sparse s = b*1024 + j*16 + k, i=(j+1+k)&63.
//
// Staging (floats, in d_out's eout region, dead before eoutT writes):
//   Qs @0, Ks @1048576, Vs @2097152, PEs @3145728,
//   relT2 @5242880 [b][c=i/8][jh][i%8] (8.4M), adjT2 @13631488 [b][c][j][i%8] (1M).
//   d_ws: scsp [262144*8] @0, M2 [576] @2097152, Tm [73*64] @2098176.
// NOTE VGPR cap = f(threads,minwaves); exceeding -> spill (WRITE_SIZE alarm, r2/3/12/15).
// NOTE r15/r16 meta-results: (1) the attn wall = ISSUE PATTERN; bulk wide loads
// stream at 2.9TB/s even at low occupancy; loads interleaved with dependent
// compute idle at ~750GB/s. (2) eoutT was LDS-ISSUE-bound: 2 b128/16 FMA-inst
// = 110K cyc/CU = 46us (one LDS unit/CU). r17 eoutT: ZERO LDS -- ev[72] in
// regs (bulk), weights via wave-uniform s_load (scalar pipe, parallel to VALU).

// qkv (blocks 0..255) + pe (256..767) + rel/adj transpose (768..1023).
__global__ __launch_bounds__(512, 2) void qkvpe_kernel(
    const float* __restrict__ h,
    const float* __restrict__ e,
    const float* __restrict__ adj2,
    const float* __restrict__ rel,
    const float* __restrict__ Wq, const float* __restrict__ bq,
    const float* __restrict__ Wk, const float* __restrict__ bk,
    const float* __restrict__ Wv, const float* __restrict__ bv,
    const float* __restrict__ Wpe, const float* __restrict__ bpe,
    float* __restrict__ Qs, float* __restrict__ Ks, float* __restrict__ Vs,
    float* __restrict__ PEs, float* __restrict__ relT, float* __restrict__ adjT)
{
    __shared__ float shA[64 * 65];   // adj transpose tile [j][i]
    __shared__ float shR[8 * 576];   // rel transpose tile [i8][(jh/8)*9 + jh%8]
    const int t = threadIdx.x;
    if (blockIdx.x < 256) {
        const int b    = blockIdx.x;
        const int lane = t & 63;
        const int wu   = __builtin_amdgcn_readfirstlane(t >> 6);   // 8 cols per wave
        const float* hrow = h + (size_t)(b * 64 + lane) * 64;
        float accQ[8], accK[8], accV[8];
        #pragma unroll
        for (int cc = 0; cc < 8; ++cc) {
            const int c = wu * 8 + cc;
            accQ[cc] = bq[c]; accK[cc] = bk[c]; accV[cc] = bv[c];
        }
        #pragma unroll 1
        for (int k0 = 0; k0 < 4; ++k0) {
            float hv[16];
            #pragma unroll
            for (int u = 0; u < 4; ++u) {
                const float4 x = ((const float4*)hrow)[k0 * 4 + u];
                hv[u*4+0] = x.x; hv[u*4+1] = x.y; hv[u*4+2] = x.z; hv[u*4+3] = x.w;
            }
            #pragma unroll
            for (int cc = 0; cc < 8; ++cc) {
                const int c = wu * 8 + cc;
                const float* wq  = Wq + c * 64 + k0 * 16;   // wave-uniform -> s_load
                const float* wk  = Wk + c * 64 + k0 * 16;
                const float* wvp = Wv + c * 64 + k0 * 16;
                #pragma unroll
                for (int k = 0; k < 16; ++k) {
                    accQ[cc] = fmaf(hv[k], wq[k],  accQ[cc]);
                    accK[cc] = fmaf(hv[k], wk[k],  accK[cc]);
                    accV[cc] = fmaf(hv[k], wvp[k], accV[cc]);
                }
            }
        }
        const size_t o = (size_t)(b * 64 + lane) * 64 + wu * 8;
        *(float4*)(Qs + o)     = make_float4(accQ[0], accQ[1], accQ[2], accQ[3]);
        *(float4*)(Qs + o + 4) = make_float4(accQ[4], accQ[5], accQ[6], accQ[7]);
        *(float4*)(Ks + o)     = make_float4(accK[0], accK[1], accK[2], accK[3]);
        *(float4*)(Ks + o + 4) = make_float4(accK[4], accK[5], accK[6], accK[7]);
        *(float4*)(Vs + o)     = make_float4(accV[0], accV[1], accV[2], accV[3]);
        *(float4*)(Vs + o + 4) = make_float4(accV[4], accV[5], accV[6], accV[7]);
    } else if (blockIdx.x < 768) {
        const int row = (blockIdx.x - 256) * 512 + t;      // 0..ES-1
        const float* erow = e + (size_t)row * 64;
        float acc[8];
        #pragma unroll
        for (int h2 = 0; h2 < 8; ++h2) acc[h2] = bpe[h2];
        #pragma unroll 1
        for (int k0 = 0; k0 < 4; ++k0) {
            float ev[16];
            #pragma unroll
            for (int u = 0; u < 4; ++u) {
                const float4 x = ((const float4*)erow)[k0 * 4 + u];
                ev[u*4+0] = x.x; ev[u*4+1] = x.y; ev[u*4+2] = x.z; ev[u*4+3] = x.w;
            }
            #pragma unroll
            for (int h2 = 0; h2 < 8; ++h2) {
                const float* wp = Wpe + h2 * 64 + k0 * 16;  // uniform -> s_load
                #pragma unroll
                for (int k = 0; k < 16; ++k)
                    acc[h2] = fmaf(ev[k], wp[k], acc[h2]);
            }
        }
        float* p0 = PEs + (size_t)row * 8;
        *(float4*)(p0)     = make_float4(acc[0], acc[1], acc[2], acc[3]);
        *(float4*)(p0 + 4) = make_float4(acc[4], acc[5], acc[6], acc[7]);
    } else {
        const int b = blockIdx.x - 768;
        // adj [i][j] -> adjT2 [c][j][d] (d = i%8, c = i/8)
        {
            const float* ap = adj2 + (size_t)b * 4096 + t * 8;   // i=t>>3, j0=(t&7)*8
            #pragma unroll
            for (int d = 0; d < 8; ++d)
                shA[((t & 7) * 8 + d) * 65 + (t >> 3)] = ap[d];
        }
        __syncthreads();
        {
            const int j = t & 63, c = t >> 6;                    // c 0..7
            float* op = adjT + (size_t)b * 4096 + c * 512 + j * 8;
            #pragma unroll
            for (int d = 0; d < 8; ++d)
                op[d] = shA[j * 65 + c * 8 + d];
        }
        // rel [i][jh] -> relT2 [c][jh][d], 8 chunks of 8 i-rows
        #pragma unroll 1
        for (int c = 0; c < 8; ++c) {
            __syncthreads();
            {
                const float* rp = rel + (size_t)b * 32768 + c * 4096 + t * 8;
                const int i8 = t >> 6;
                const int g  = t & 63;                 // jh = g*8 + d
                #pragma unroll
                for (int d = 0; d < 8; ++d)
                    shR[i8 * 576 + g * 9 + d] = rp[d];
            }
            __syncthreads();
            {
                float* op = relT + (size_t)b * 32768 + c * 4096 + t * 8;  // jh = t
                #pragma unroll
                for (int i8 = 0; i8 < 8; ++i8)
                    op[i8] = shR[i8 * 576 + (t >> 3) * 9 + (t & 7)];
            }
        }
    }
}

// attn: 512 blocks = (b, jhalf), 256 threads = (jl = t>>3, hh = t&7).
// R[64] rel prefetched in one contiguous burst; adj/K/V/PE in LDS; loop fully
// unrolled, zero in-loop global memory; full 64-i per thread -> NO reductions.
__global__ __launch_bounds__(256, 1) void attn_kernel(
    const float* __restrict__ Qs, const float* __restrict__ Ks,
    const float* __restrict__ Vs, const float* __restrict__ PEs,
    const float* __restrict__ adjT,
    const float* __restrict__ relT,
    float* __restrict__ wVg,          // [16384*64] = h_out region (normalized wV)
    float* __restrict__ scsp)
{
    __shared__ float shK[64 * 64];    // [i][dim], plain (broadcast rows)
    __shared__ float shV[64 * 64];
    __shared__ float shPE[512 * 8];   // this j-half's proj_e -> sc in place
    __shared__ float shAdj[64 * 33];  // [i][jl]

    const int b2 = blockIdx.x;
    const int b  = b2 >> 1;
    const int j0 = (b2 & 1) << 5;
    const int t  = threadIdx.x;
    const int jl = t >> 3;
    const int hh = t & 7;
    const int j  = j0 + jl;

    // ---- bulk register prefetch: R[64] (this thread's rel row, chunk layout)
    const float* rT = relT + (size_t)b * 32768 + (size_t)j0 * 64 + t * 8;
    float R[64];
    #pragma unroll
    for (int c = 0; c < 8; ++c) {
        const float4 x = *(const float4*)(rT + c * 4096);
        const float4 y = *(const float4*)(rT + c * 4096 + 4);
        R[c*8+0] = x.x; R[c*8+1] = x.y; R[c*8+2] = x.z; R[c*8+3] = x.w;
        R[c*8+4] = y.x; R[c*8+5] = y.y; R[c*8+6] = y.z; R[c*8+7] = y.w;
    }
    // ---- stage K, V, PE slice, adj (coalesced); q per-thread
    {
        const float4* srcK = (const float4*)(Ks + (size_t)b * 4096);
        const float4* srcV = (const float4*)(Vs + (size_t)b * 4096);
        float4* dK = (float4*)shK; float4* dV = (float4*)shV;
        #pragma unroll
        for (int u = 0; u < 4; ++u) {
            dK[u * 256 + t] = srcK[u * 256 + t];
            dV[u * 256 + t] = srcV[u * 256 + t];
        }
        const float4* srcP = (const float4*)(PEs + ((size_t)b * 1024 + j0 * 16) * 8);
        float4* dP = (float4*)shPE;
        #pragma unroll
        for (int u = 0; u < 4; ++u)
            dP[u * 256 + t] = srcP[u * 256 + t];
    }
    {   // adj: thread t -> chunk c = t>>5, j = j0 + (t&31); 8 d-values
        const int c = t >> 5, o = t & 31;
        const float4 a0 = *(const float4*)(adjT + (size_t)b * 4096 + c * 512 + (j0 + o) * 8);
        const float4 a1 = *(const float4*)(adjT + (size_t)b * 4096 + c * 512 + (j0 + o) * 8 + 4);
        shAdj[(c*8+0) * 33 + o] = a0.x; shAdj[(c*8+1) * 33 + o] = a0.y;
        shAdj[(c*8+2) * 33 + o] = a0.z; shAdj[(c*8+3) * 33 + o] = a0.w;
        shAdj[(c*8+4) * 33 + o] = a1.x; shAdj[(c*8+5) * 33 + o] = a1.y;
        shAdj[(c*8+6) * 33 + o] = a1.z; shAdj[(c*8+7) * 33 + o] = a1.w;
    }
    float q[8];
    {
        const float* qp = Qs + (size_t)(b * 64 + j) * 64 + hh * 8;
        const float4 a = *(const float4*)qp;
        const float4 c4 = *(const float4*)(qp + 4);
        q[0]=a.x; q[1]=a.y; q[2]=a.z; q[3]=a.w;
        q[4]=c4.x; q[5]=c4.y; q[6]=c4.z; q[7]=c4.w;
    }
    __syncthreads();

    // ---- i-loop: pure regs + LDS broadcast, fully unrolled (R[i] static)
    float den = 0.f;
    float wv[8] = {0.f,0.f,0.f,0.f,0.f,0.f,0.f,0.f};
    const float inv_scale = 0.35355339059327379f;  // 1/sqrt(8)
    #pragma unroll
    for (int i = 0; i < 64; ++i) {
        const float4 kA = *(const float4*)&shK[i * 64 + hh * 8];
        const float4 kC = *(const float4*)&shK[i * 64 + hh * 8 + 4];
        float s = kA.x * q[0];
        s = fmaf(kA.y, q[1], s); s = fmaf(kA.z, q[2], s); s = fmaf(kA.w, q[3], s);
        s = fmaf(kC.x, q[4], s); s = fmaf(kC.y, q[5], s); s = fmaf(kC.z, q[6], s);
        s = fmaf(kC.w, q[7], s);
        s = fmaf(s * inv_scale, shAdj[i * 33 + jl], R[i]);   // raw score
        const int kidx = (i - j - 1) & 63;
        if (kidx < 16) {                          // sparse edge, unique owner
            const int x = (jl * 16 + kidx) * 8 + hh;
            const float pe = shPE[x];             // read proj_e once
            shPE[x] = s;                          // overwrite with sc_sp in place
            s += pe;                              // softmax sees sc + proj_e
        }
        s = fminf(fmaxf(s, -5.f), 5.f);
        const float ex = __expf(s);
        den += ex;
        const float4 vA = *(const float4*)&shV[i * 64 + hh * 8];
        const float4 vC = *(const float4*)&shV[i * 64 + hh * 8 + 4];
        wv[0] = fmaf(ex, vA.x, wv[0]); wv[1] = fmaf(ex, vA.y, wv[1]);
        wv[2] = fmaf(ex, vA.z, wv[2]); wv[3] = fmaf(ex, vA.w, wv[3]);
        wv[4] = fmaf(ex, vC.x, wv[4]); wv[5] = fmaf(ex, vC.y, wv[5]);
        wv[6] = fmaf(ex, vC.z, wv[6]); wv[7] = fmaf(ex, vC.w, wv[7]);
    }
    __syncthreads();                 // all PE->SC swaps complete

    // ---- coalesced sc dump + normalized wV out
    {
        const float4* src = (const float4*)shPE;
        float4* dst = (float4*)(scsp + ((size_t)b * 1024 + j0 * 16) * 8);
        #pragma unroll
        for (int u = 0; u < 4; ++u)
            dst[u * 256 + t] = src[u * 256 + t];
    }
    const float id = 1.f / den;
    float* wp = wVg + (size_t)(b * 64 + j) * 64 + hh * 8;
    *(float4*)(wp)     = make_float4(wv[0]*id, wv[1]*id, wv[2]*id, wv[3]*id);
    *(float4*)(wp + 4) = make_float4(wv[4]*id, wv[5]*id, wv[6]*id, wv[7]*id);
}

// hout: h_out = wVg @ Wo^T + bo, 4x4 micro-tile; wVg lives IN h_out region.
__global__ __launch_bounds__(256, 2) void hout_kernel(
    const float* __restrict__ wVg,
    const float* __restrict__ Wo, const float* __restrict__ bo,
    float* __restrict__ h_out)
{
    __shared__ float shWT[64 * 69];
    __shared__ float shWoT[64 * 65];

    const int t    = threadIdx.x;
    const int base = blockIdx.x * 64;
    {
        const int r0 = t >> 2, qq = t & 3;
        const float* ep = wVg + (size_t)(base + r0) * 64 + qq * 16;
        #pragma unroll
        for (int v = 0; v < 4; ++v) {
            const float4 x = ((const float4*)ep)[v];
            const int c = qq * 16 + v * 4;
            shWT[(c + 0) * 69 + r0] = x.x;
            shWT[(c + 1) * 69 + r0] = x.y;
            shWT[(c + 2) * 69 + r0] = x.z;
            shWT[(c + 3) * 69 + r0] = x.w;
        }
    }
    {
        const int c0 = t >> 2, qq = t & 3;
        const float* wp = Wo + c0 * 64 + qq * 16;
        #pragma unroll
        for (int v = 0; v < 4; ++v) {
            const float4 x = ((const float4*)wp)[v];
            const int k = qq * 16 + v * 4;
            shWoT[(k + 0) * 65 + c0] = x.x;
            shWoT[(k + 1) * 65 + c0] = x.y;
            shWoT[(k + 2) * 65 + c0] = x.z;
            shWoT[(k + 3) * 65 + c0] = x.w;
        }
    }
    __syncthreads();

    const int rq = t >> 4, cq = t & 15;
    float acc[16];
    {
        const float4 bv = *(const float4*)(bo + cq * 4);
        #pragma unroll
        for (int ri = 0; ri < 4; ++ri) {
            acc[ri*4+0] = bv.x; acc[ri*4+1] = bv.y;
            acc[ri*4+2] = bv.z; acc[ri*4+3] = bv.w;
        }
    }
    #pragma unroll
    for (int k = 0; k < 64; ++k) {
        const float4 ev = *(const float4*)&shWT[k * 69 + rq * 4];
        const float4 wk = *(const float4*)&shWoT[k * 65 + cq * 4];
        acc[0]  = fmaf(ev.x, wk.x, acc[0]);  acc[1]  = fmaf(ev.x, wk.y, acc[1]);
        acc[2]  = fmaf(ev.x, wk.z, acc[2]);  acc[3]  = fmaf(ev.x, wk.w, acc[3]);
        acc[4]  = fmaf(ev.y, wk.x, acc[4]);  acc[5]  = fmaf(ev.y, wk.y, acc[5]);
        acc[6]  = fmaf(ev.y, wk.z, acc[6]);  acc[7]  = fmaf(ev.y, wk.w, acc[7]);
        acc[8]  = fmaf(ev.z, wk.x, acc[8]);  acc[9]  = fmaf(ev.z, wk.y, acc[9]);
        acc[10] = fmaf(ev.z, wk.z, acc[10]); acc[11] = fmaf(ev.z, wk.w, acc[11]);
        acc[12] = fmaf(ev.w, wk.x, acc[12]); acc[13] = fmaf(ev.w, wk.y, acc[13]);
        acc[14] = fmaf(ev.w, wk.z, acc[14]); acc[15] = fmaf(ev.w, wk.w, acc[15]);
    }
    #pragma unroll
    for (int ri = 0; ri < 4; ++ri) {
        float* orow = h_out + (size_t)(base + rq * 4 + ri) * 64 + cq * 4;
        *(float4*)orow = make_float4(acc[ri*4+0], acc[ri*4+1], acc[ri*4+2], acc[ri*4+3]);
    }
}

// prep: M2/bc (fallback) + T[73][64] = [Woe^T ; M2^T ; bc].
__global__ void prep_kernel(const float* __restrict__ Wap, const float* __restrict__ bap,
                            const float* __restrict__ Woe, const float* __restrict__ boe,
                            float* __restrict__ M2, float* __restrict__ Tm, int hasT)
{
    const int tg = blockIdx.x * 64 + threadIdx.x;
    if (tg < 512) {
        const int c = tg >> 3, hq = tg & 7;
        float s = 0.f;
        #pragma unroll 8
        for (int k = 0; k < 64; ++k) s = fmaf(Woe[c * 64 + k], Wap[k * 8 + hq], s);
        M2[tg] = s;
    } else if (tg < 576) {
        const int c = tg - 512;
        float s = boe[c];
        #pragma unroll 8
        for (int k = 0; k < 64; ++k) s = fmaf(bap[k], Woe[c * 64 + k], s);
        M2[512 + c] = s;
    } else if (hasT && tg < 576 + 73 * 64) {
        const int idx = tg - 576;
        const int k = idx >> 6, c = idx & 63;
        float v;
        if (k < 64) {
            v = Woe[c * 64 + k];
        } else if (k < 72) {
            const int hq = k - 64;
            v = 0.f;
            #pragma unroll 8
            for (int kk = 0; kk < 64; ++kk)
                v = fmaf(Woe[c * 64 + kk], Wap[kk * 8 + hq], v);
        } else {
            v = boe[c];
            #pragma unroll 8
            for (int kk = 0; kk < 64; ++kk)
                v = fmaf(bap[kk], Woe[c * 64 + kk], v);
        }
        Tm[k * 64 + c] = v;
    }
}

// eoutT: ZERO-LDS flat k-outer. 256 thr = 64 rows x 4 col-groups(16 cols).
// ev[72] (e-row + sc-row) bulk-loaded to regs (18 b128 upfront); weights/bc via
// wave-uniform s_load_dwordx16 per k (scalar pipe, no LDS-unit contention).
// Fully unrolled k-loop -> static ev indices. VGPR ~110, no LDS.
__global__ __launch_bounds__(256, 2) void eoutT_kernel(
    const float* __restrict__ e,
    const float* __restrict__ scsp,
    const float* __restrict__ Tm,      // [73][64]: Woe^T k=0..63, M2^T k=64..71, bc
    float* __restrict__ e_out)
{
    const int t   = threadIdx.x;
    const int r   = t & 63;
    const int w   = __builtin_amdgcn_readfirstlane(t >> 6);   // col group 0..3
    const int row = blockIdx.x * 64 + r;

    float ev[72];
    {
        const float* ep = e + (size_t)row * 64;
        #pragma unroll
        for (int v = 0; v < 16; ++v) {
            const float4 x = ((const float4*)ep)[v];
            ev[v*4+0] = x.x; ev[v*4+1] = x.y; ev[v*4+2] = x.z; ev[v*4+3] = x.w;
        }
        const float4 s0 = *(const float4*)(scsp + (size_t)row * 8);
        const float4 s1 = *(const float4*)(scsp + (size_t)row * 8 + 4);
        ev[64]=s0.x; ev[65]=s0.y; ev[66]=s0.z; ev[67]=s0.w;
        ev[68]=s1.x; ev[69]=s1.y; ev[70]=s1.z; ev[71]=s1.w;
    }
    const float* wbase = Tm + w * 16;              // wave-uniform
    float acc[16];
    #pragma unroll
    for (int u = 0; u < 16; ++u) acc[u] = wbase[72 * 64 + u];   // bc via s_load
    #pragma unroll
    for (int k = 0; k < 72; ++k) {
        const float* wk = wbase + k * 64;          // wave-uniform -> s_load_dwordx16
        #pragma unroll
        for (int u = 0; u < 16; ++u)
            acc[u] = fmaf(ev[k], wk[u], acc[u]);   // 16 independent FMAs
    }
    float* orow = e_out + (size_t)row * 64 + w * 16;
    #pragma unroll
    for (int u = 0; u < 4; ++u)
        *(float4*)&orow[u * 4] =
            make_float4(acc[u*4+0], acc[u*4+1], acc[u*4+2], acc[u*4+3]);
}

// Fallback eout if d_ws can't hold Tm (r10 shape).
__global__ __launch_bounds__(256, 2) void eout_kernel(
    const float* __restrict__ e,
    const float* __restrict__ scsp,
    const float* __restrict__ Woe,
    const float* __restrict__ M2g,
    float* __restrict__ e_out)
{
    __shared__ float shE[64 * 64];
    __shared__ float shS[64 * 8];
    const int t    = threadIdx.x;
    const int base = blockIdx.x * 64;
    {
        const int r = t >> 2, qq = t & 3;
        const float* ep = e + (size_t)(base + r) * 64 + qq * 16;
        #pragma unroll
        for (int u = 0; u < 4; ++u) {
            const float4 x = ((const float4*)ep)[u];
            const int cc = qq * 4 + u;
            *(float4*)&shE[r * 64 + ((cc ^ (r & 15)) << 2)] = x;
        }
    }
    if (t < 128) {
        const int r = t >> 1, pp = t & 1;
        *(float4*)&shS[r * 8 + pp * 4] =
            *(const float4*)(scsp + (size_t)(base + r) * 8 + pp * 4);
    }
    __syncthreads();
    const int w = __builtin_amdgcn_readfirstlane(t >> 6);
    const int r = t & 63;
    float sc[8];
    {
        const float4 a  = *(const float4*)&shS[r * 8];
        const float4 c4 = *(const float4*)&shS[r * 8 + 4];
        sc[0]=a.x; sc[1]=a.y; sc[2]=a.z; sc[3]=a.w;
        sc[4]=c4.x; sc[5]=c4.y; sc[6]=c4.z; sc[7]=c4.w;
    }
    float acc[16];
    #pragma unroll
    for (int u = 0; u < 16; ++u) {
        const int c = w * 16 + u;
        float s = M2g[512 + c];
        #pragma unroll
        for (int hq = 0; hq < 8; ++hq)
            s = fmaf(sc[hq], M2g[c * 8 + hq], s);
        acc[u] = s;
    }
    #pragma unroll
    for (int k0 = 0; k0 < 4; ++k0) {
        float ev[16];
        #pragma unroll
        for (int v = 0; v < 4; ++v) {
            const int cc = k0 * 4 + v;
            const float4 x = *(const float4*)&shE[r * 64 + ((cc ^ (r & 15)) << 2)];
            ev[v*4+0] = x.x; ev[v*4+1] = x.y; ev[v*4+2] = x.z; ev[v*4+3] = x.w;
        }
        #pragma unroll
        for (int u = 0; u < 16; ++u) {
            const float* wr = Woe + (w * 16 + u) * 64 + k0 * 16;
            #pragma unroll
            for (int k = 0; k < 16; ++k)
                acc[u] = fmaf(ev[k], wr[k], acc[u]);
        }
    }
    float* orow = e_out + (size_t)(base + r) * 64 + w * 16;
    #pragma unroll
    for (int u = 0; u < 4; ++u)
        *(float4*)&orow[u * 4] =
            make_float4(acc[u*4+0], acc[u*4+1], acc[u*4+2], acc[u*4+3]);
}

extern "C" void kernel_launch(void* const* d_in, const int* in_sizes, int n_in,
                              void* d_out, int out_size, void* d_ws, size_t ws_size,
                              hipStream_t stream) {
    const float* h    = (const float*)d_in[0];
    const float* e    = (const float*)d_in[1];
    const float* adj2 = (const float*)d_in[2];
    const float* rel  = (const float*)d_in[3];
    const float* Wq   = (const float*)d_in[4];  const float* bq  = (const float*)d_in[5];
    const float* Wk   = (const float*)d_in[6];  const float* bk  = (const float*)d_in[7];
    const float* Wv   = (const float*)d_in[8];  const float* bv  = (const float*)d_in[9];
    const float* Wpe  = (const float*)d_in[10]; const float* bpe = (const float*)d_in[11];
    const float* Wap  = (const float*)d_in[12]; const float* bap = (const float*)d_in[13];
    const float* Wo   = (const float*)d_in[14]; const float* bo  = (const float*)d_in[15];
    const float* Woe  = (const float*)d_in[16]; const float* boe = (const float*)d_in[17];

    float* out  = (float*)d_out;
    float* hout = out;                        // [16384*64]; holds wVg between kernels
    float* eout = out + 16384 * 64;           // [262144*64], staging (dead at eout time)
    float* Qs   = eout;
    float* Ks   = eout + 1048576;
    float* Vs   = eout + 2097152;
    float* PEs  = eout + 3145728;             // ends 5242880
    float* relT = eout + 5242880;             // chunked [b][c][jh][d] -> ends 13631488
    float* adjT = eout + 13631488;            // chunked [b][c][j][d]  -> ends 14680064
    float* ws   = (float*)d_ws;
    float* scsp = ws;                         // [262144*8]
    float* M2g  = ws + 2097152;               // [576]
    float* Tm   = ws + 2098176;               // [73*64]
    const int hasT = (ws_size >= (size_t)(2098176 + 73 * 64) * sizeof(float)) ? 1 : 0;

    prep_kernel<<<dim3(82), dim3(64), 0, stream>>>(Wap, bap, Woe, boe, M2g, Tm, hasT);
    qkvpe_kernel<<<dim3(1024), dim3(512), 0, stream>>>(
        h, e, adj2, rel, Wq, bq, Wk, bk, Wv, bv, Wpe, bpe,
        Qs, Ks, Vs, PEs, relT, adjT);
    attn_kernel<<<dim3(512), dim3(256), 0, stream>>>(
        Qs, Ks, Vs, PEs, adjT, relT, hout /*wVg*/, scsp);
    hout_kernel<<<dim3(256), dim3(256), 0, stream>>>(hout, Wo, bo, hout);
    if (hasT)
        eoutT_kernel<<<dim3(4096), dim3(256), 0, stream>>>(e, scsp, Tm, eout);
    else
        eout_kernel<<<dim3(4096), dim3(256), 0, stream>>>(e, scsp, Woe, M2g, eout);
}

// Round 18
// 142.869 us; speedup vs baseline: 1.5625x; 1.0195x over previous
//
#include <hip/hip_runtime.h>

// Geometry: G=256 graphs x 64 nodes, H=8 heads x D=8, IN_DIM=EDGE_DIM=64
// EF = 1048576 full edges, ES = 262144 sparse edges.
// edge f = b*4096 + i*64 + j (src=i, dst=j); sparse s = b*1024 + j*16 + k, i=(j+1+k)&63.
//
// Staging (floats, d_out's eout region, dead before eoutT writes):
//   Qs @0, Ks @1048576, Vs @2097152, PEs @3145728.
//   d_ws: scsp [262144*8] @0, M2 [576] @2097152, Tm [73*64] @2098176.
// NOTE VGPR cap = f(threads,minwaves); exceeding -> spill (WRITE_SIZE alarm).
// NOTE meta-results r15-r17: (1) walls = ISSUE PATTERN: bulk-issued wide/
// coalesced loads stream at 2.9TB/s even at low occupancy; loads interleaved
// with dependent compute (or barrier-chunked staging) idle at ~750GB/s.
// (2) LDS-unit issue (one/CU) bounds any kernel with >1 b128 per ~8 FMA-insts.
// (3) co-compiled multi-branch kernels share regalloc (r17 qkvpe: VGPR 28!) --
// keep branch count low, check VGPR per round. (4) NO transposes through
// barrier-chunked LDS: rel is already per-i wave-coalesced (256B runs).

// qkv (blocks 0..255) + pe (blocks 256..767), independent. (r14-proven ~19us)
__global__ __launch_bounds__(512, 2) void qkvpe_kernel(
    const float* __restrict__ h,
    const float* __restrict__ e,
    const float* __restrict__ Wq, const float* __restrict__ bq,
    const float* __restrict__ Wk, const float* __restrict__ bk,
    const float* __restrict__ Wv, const float* __restrict__ bv,
    const float* __restrict__ Wpe, const float* __restrict__ bpe,
    float* __restrict__ Qs, float* __restrict__ Ks, float* __restrict__ Vs,
    float* __restrict__ PEs)
{
    const int t = threadIdx.x;
    if (blockIdx.x < 256) {
        const int b    = blockIdx.x;
        const int lane = t & 63;
        const int wu   = __builtin_amdgcn_readfirstlane(t >> 6);   // 8 cols per wave
        const float* hrow = h + (size_t)(b * 64 + lane) * 64;
        float accQ[8], accK[8], accV[8];
        #pragma unroll
        for (int cc = 0; cc < 8; ++cc) {
            const int c = wu * 8 + cc;
            accQ[cc] = bq[c]; accK[cc] = bk[c]; accV[cc] = bv[c];
        }
        #pragma unroll 1
        for (int k0 = 0; k0 < 4; ++k0) {
            float hv[16];
            #pragma unroll
            for (int u = 0; u < 4; ++u) {
                const float4 x = ((const float4*)hrow)[k0 * 4 + u];
                hv[u*4+0] = x.x; hv[u*4+1] = x.y; hv[u*4+2] = x.z; hv[u*4+3] = x.w;
            }
            #pragma unroll
            for (int cc = 0; cc < 8; ++cc) {
                const int c = wu * 8 + cc;
                const float* wq  = Wq + c * 64 + k0 * 16;   // wave-uniform -> s_load
                const float* wk  = Wk + c * 64 + k0 * 16;
                const float* wvp = Wv + c * 64 + k0 * 16;
                #pragma unroll
                for (int k = 0; k < 16; ++k) {
                    accQ[cc] = fmaf(hv[k], wq[k],  accQ[cc]);
                    accK[cc] = fmaf(hv[k], wk[k],  accK[cc]);
                    accV[cc] = fmaf(hv[k], wvp[k], accV[cc]);
                }
            }
        }
        const size_t o = (size_t)(b * 64 + lane) * 64 + wu * 8;
        *(float4*)(Qs + o)     = make_float4(accQ[0], accQ[1], accQ[2], accQ[3]);
        *(float4*)(Qs + o + 4) = make_float4(accQ[4], accQ[5], accQ[6], accQ[7]);
        *(float4*)(Ks + o)     = make_float4(accK[0], accK[1], accK[2], accK[3]);
        *(float4*)(Ks + o + 4) = make_float4(accK[4], accK[5], accK[6], accK[7]);
        *(float4*)(Vs + o)     = make_float4(accV[0], accV[1], accV[2], accV[3]);
        *(float4*)(Vs + o + 4) = make_float4(accV[4], accV[5], accV[6], accV[7]);
    } else {
        const int row = (blockIdx.x - 256) * 512 + t;      // 0..ES-1
        const float* erow = e + (size_t)row * 64;
        float acc[8];
        #pragma unroll
        for (int h2 = 0; h2 < 8; ++h2) acc[h2] = bpe[h2];
        #pragma unroll 1
        for (int k0 = 0; k0 < 4; ++k0) {
            float ev[16];
            #pragma unroll
            for (int u = 0; u < 4; ++u) {
                const float4 x = ((const float4*)erow)[k0 * 4 + u];
                ev[u*4+0] = x.x; ev[u*4+1] = x.y; ev[u*4+2] = x.z; ev[u*4+3] = x.w;
            }
            #pragma unroll
            for (int h2 = 0; h2 < 8; ++h2) {
                const float* wp = Wpe + h2 * 64 + k0 * 16;  // uniform -> s_load
                #pragma unroll
                for (int k = 0; k < 16; ++k)
                    acc[h2] = fmaf(ev[k], wp[k], acc[h2]);
            }
        }
        float* p0 = PEs + (size_t)row * 8;
        *(float4*)(p0)     = make_float4(acc[0], acc[1], acc[2], acc[3]);
        *(float4*)(p0 + 4) = make_float4(acc[4], acc[5], acc[6], acc[7]);
    }
}

// attn: 512 blocks = (b, jhalf), 256 threads = (jl = t>>3, hh = t&7).
// R[64] = 64 fully-unrolled SCALAR loads from original rel (per-i the wave
// reads 256 consecutive bytes; all 64 issued in bulk before the barrier).
// adj -> LDS directly from original layout. Loop = regs + LDS broadcast only.
__global__ __launch_bounds__(256, 1) void attn_kernel(
    const float* __restrict__ Qs, const float* __restrict__ Ks,
    const float* __restrict__ Vs, const float* __restrict__ PEs,
    const float* __restrict__ adj2,
    const float* __restrict__ rel,
    float* __restrict__ wVg,          // [16384*64] = h_out region (normalized wV)
    float* __restrict__ scsp)
{
    __shared__ float shK[64 * 64];    // [i][dim], plain (broadcast rows)
    __shared__ float shV[64 * 64];
    __shared__ float shPE[512 * 8];   // this j-half's proj_e -> sc in place
    __shared__ float shAdj[64 * 33];  // [i][jl]

    const int b2 = blockIdx.x;
    const int b  = b2 >> 1;
    const int j0 = (b2 & 1) << 5;
    const int t  = threadIdx.x;
    const int jl = t >> 3;
    const int hh = t & 7;
    const int j  = j0 + jl;

    // ---- bulk register prefetch: R[i] = rel[b][i][j][hh]; addr = base + i*512
    // (per-i: lanes t..t+63 consecutive -> 256B coalesced; 64 independent loads)
    const float* relBase = rel + (size_t)b * 32768 + j0 * 8 + t;
    float R[64];
    #pragma unroll
    for (int i = 0; i < 64; ++i)
        R[i] = relBase[(size_t)i * 512];

    // ---- stage K, V, PE slice (coalesced), adj (128B segments); q per-thread
    {
        const float4* srcK = (const float4*)(Ks + (size_t)b * 4096);
        const float4* srcV = (const float4*)(Vs + (size_t)b * 4096);
        float4* dK = (float4*)shK; float4* dV = (float4*)shV;
        #pragma unroll
        for (int u = 0; u < 4; ++u) {
            dK[u * 256 + t] = srcK[u * 256 + t];
            dV[u * 256 + t] = srcV[u * 256 + t];
        }
        const float4* srcP = (const float4*)(PEs + ((size_t)b * 1024 + j0 * 16) * 8);
        float4* dP = (float4*)shPE;
        #pragma unroll
        for (int u = 0; u < 4; ++u)
            dP[u * 256 + t] = srcP[u * 256 + t];
    }
    {   // adj: thread (i2 = t>>2, grp = t&3) loads 8 j's of row i2
        const int i2 = t >> 2, grp = t & 3;
        const float* ap = adj2 + (size_t)b * 4096 + i2 * 64 + j0 + grp * 8;
        const float4 a0 = *(const float4*)(ap);
        const float4 a1 = *(const float4*)(ap + 4);
        float* dp = &shAdj[i2 * 33 + grp * 8];
        dp[0] = a0.x; dp[1] = a0.y; dp[2] = a0.z; dp[3] = a0.w;
        dp[4] = a1.x; dp[5] = a1.y; dp[6] = a1.z; dp[7] = a1.w;
    }
    float q[8];
    {
        const float* qp = Qs + (size_t)(b * 64 + j) * 64 + hh * 8;
        const float4 a = *(const float4*)qp;
        const float4 c4 = *(const float4*)(qp + 4);
        q[0]=a.x; q[1]=a.y; q[2]=a.z; q[3]=a.w;
        q[4]=c4.x; q[5]=c4.y; q[6]=c4.z; q[7]=c4.w;
    }
    __syncthreads();

    // ---- i-loop: pure regs + LDS broadcast, fully unrolled (R[i] static)
    float den = 0.f;
    float wv[8] = {0.f,0.f,0.f,0.f,0.f,0.f,0.f,0.f};
    const float inv_scale = 0.35355339059327379f;  // 1/sqrt(8)
    #pragma unroll
    for (int i = 0; i < 64; ++i) {
        const float4 kA = *(const float4*)&shK[i * 64 + hh * 8];
        const float4 kC = *(const float4*)&shK[i * 64 + hh * 8 + 4];
        float s = kA.x * q[0];
        s = fmaf(kA.y, q[1], s); s = fmaf(kA.z, q[2], s); s = fmaf(kA.w, q[3], s);
        s = fmaf(kC.x, q[4], s); s = fmaf(kC.y, q[5], s); s = fmaf(kC.z, q[6], s);
        s = fmaf(kC.w, q[7], s);
        s = fmaf(s * inv_scale, shAdj[i * 33 + jl], R[i]);   // raw score
        const int kidx = (i - j - 1) & 63;
        if (kidx < 16) {                          // sparse edge, unique owner
            const int x = (jl * 16 + kidx) * 8 + hh;
            const float pe = shPE[x];             // read proj_e once
            shPE[x] = s;                          // overwrite with sc_sp in place
            s += pe;                              // softmax sees sc + proj_e
        }
        s = fminf(fmaxf(s, -5.f), 5.f);
        const float ex = __expf(s);
        den += ex;
        const float4 vA = *(const float4*)&shV[i * 64 + hh * 8];
        const float4 vC = *(const float4*)&shV[i * 64 + hh * 8 + 4];
        wv[0] = fmaf(ex, vA.x, wv[0]); wv[1] = fmaf(ex, vA.y, wv[1]);
        wv[2] = fmaf(ex, vA.z, wv[2]); wv[3] = fmaf(ex, vA.w, wv[3]);
        wv[4] = fmaf(ex, vC.x, wv[4]); wv[5] = fmaf(ex, vC.y, wv[5]);
        wv[6] = fmaf(ex, vC.z, wv[6]); wv[7] = fmaf(ex, vC.w, wv[7]);
    }
    __syncthreads();                 // all PE->SC swaps complete

    // ---- coalesced sc dump + normalized wV out
    {
        const float4* src = (const float4*)shPE;
        float4* dst = (float4*)(scsp + ((size_t)b * 1024 + j0 * 16) * 8);
        #pragma unroll
        for (int u = 0; u < 4; ++u)
            dst[u * 256 + t] = src[u * 256 + t];
    }
    const float id = 1.f / den;
    float* wp = wVg + (size_t)(b * 64 + j) * 64 + hh * 8;
    *(float4*)(wp)     = make_float4(wv[0]*id, wv[1]*id, wv[2]*id, wv[3]*id);
    *(float4*)(wp + 4) = make_float4(wv[4]*id, wv[5]*id, wv[6]*id, wv[7]*id);
}

// hout: h_out = wVg @ Wo^T + bo, 4x4 micro-tile; wVg lives IN h_out region.
__global__ __launch_bounds__(256, 2) void hout_kernel(
    const float* __restrict__ wVg,
    const float* __restrict__ Wo, const float* __restrict__ bo,
    float* __restrict__ h_out)
{
    __shared__ float shWT[64 * 69];
    __shared__ float shWoT[64 * 65];

    const int t    = threadIdx.x;
    const int base = blockIdx.x * 64;
    {
        const int r0 = t >> 2, qq = t & 3;
        const float* ep = wVg + (size_t)(base + r0) * 64 + qq * 16;
        #pragma unroll
        for (int v = 0; v < 4; ++v) {
            const float4 x = ((const float4*)ep)[v];
            const int c = qq * 16 + v * 4;
            shWT[(c + 0) * 69 + r0] = x.x;
            shWT[(c + 1) * 69 + r0] = x.y;
            shWT[(c + 2) * 69 + r0] = x.z;
            shWT[(c + 3) * 69 + r0] = x.w;
        }
    }
    {
        const int c0 = t >> 2, qq = t & 3;
        const float* wp = Wo + c0 * 64 + qq * 16;
        #pragma unroll
        for (int v = 0; v < 4; ++v) {
            const float4 x = ((const float4*)wp)[v];
            const int k = qq * 16 + v * 4;
            shWoT[(k + 0) * 65 + c0] = x.x;
            shWoT[(k + 1) * 65 + c0] = x.y;
            shWoT[(k + 2) * 65 + c0] = x.z;
            shWoT[(k + 3) * 65 + c0] = x.w;
        }
    }
    __syncthreads();

    const int rq = t >> 4, cq = t & 15;
    float acc[16];
    {
        const float4 bv = *(const float4*)(bo + cq * 4);
        #pragma unroll
        for (int ri = 0; ri < 4; ++ri) {
            acc[ri*4+0] = bv.x; acc[ri*4+1] = bv.y;
            acc[ri*4+2] = bv.z; acc[ri*4+3] = bv.w;
        }
    }
    #pragma unroll
    for (int k = 0; k < 64; ++k) {
        const float4 ev = *(const float4*)&shWT[k * 69 + rq * 4];
        const float4 wk = *(const float4*)&shWoT[k * 65 + cq * 4];
        acc[0]  = fmaf(ev.x, wk.x, acc[0]);  acc[1]  = fmaf(ev.x, wk.y, acc[1]);
        acc[2]  = fmaf(ev.x, wk.z, acc[2]);  acc[3]  = fmaf(ev.x, wk.w, acc[3]);
        acc[4]  = fmaf(ev.y, wk.x, acc[4]);  acc[5]  = fmaf(ev.y, wk.y, acc[5]);
        acc[6]  = fmaf(ev.y, wk.z, acc[6]);  acc[7]  = fmaf(ev.y, wk.w, acc[7]);
        acc[8]  = fmaf(ev.z, wk.x, acc[8]);  acc[9]  = fmaf(ev.z, wk.y, acc[9]);
        acc[10] = fmaf(ev.z, wk.z, acc[10]); acc[11] = fmaf(ev.z, wk.w, acc[11]);
        acc[12] = fmaf(ev.w, wk.x, acc[12]); acc[13] = fmaf(ev.w, wk.y, acc[13]);
        acc[14] = fmaf(ev.w, wk.z, acc[14]); acc[15] = fmaf(ev.w, wk.w, acc[15]);
    }
    #pragma unroll
    for (int ri = 0; ri < 4; ++ri) {
        float* orow = h_out + (size_t)(base + rq * 4 + ri) * 64 + cq * 4;
        *(float4*)orow = make_float4(acc[ri*4+0], acc[ri*4+1], acc[ri*4+2], acc[ri*4+3]);
    }
}

// prep: M2/bc (fallback) + T[73][64] = [Woe^T ; M2^T ; bc].
__global__ void prep_kernel(const float* __restrict__ Wap, const float* __restrict__ bap,
                            const float* __restrict__ Woe, const float* __restrict__ boe,
                            float* __restrict__ M2, float* __restrict__ Tm, int hasT)
{
    const int tg = blockIdx.x * 64 + threadIdx.x;
    if (tg < 512) {
        const int c = tg >> 3, hq = tg & 7;
        float s = 0.f;
        #pragma unroll 8
        for (int k = 0; k < 64; ++k) s = fmaf(Woe[c * 64 + k], Wap[k * 8 + hq], s);
        M2[tg] = s;
    } else if (tg < 576) {
        const int c = tg - 512;
        float s = boe[c];
        #pragma unroll 8
        for (int k = 0; k < 64; ++k) s = fmaf(bap[k], Woe[c * 64 + k], s);
        M2[512 + c] = s;
    } else if (hasT && tg < 576 + 73 * 64) {
        const int idx = tg - 576;
        const int k = idx >> 6, c = idx & 63;
        float v;
        if (k < 64) {
            v = Woe[c * 64 + k];
        } else if (k < 72) {
            const int hq = k - 64;
            v = 0.f;
            #pragma unroll 8
            for (int kk = 0; kk < 64; ++kk)
                v = fmaf(Woe[c * 64 + kk], Wap[kk * 8 + hq], v);
        } else {
            v = boe[c];
            #pragma unroll 8
            for (int kk = 0; kk < 64; ++kk)
                v = fmaf(bap[kk], Woe[c * 64 + kk], v);
        }
        Tm[k * 64 + c] = v;
    }
}

// eoutT: ZERO-LDS flat k-outer (r17). 256 thr = 64 rows x 4 col-groups.
// ev[72] bulk in regs; weights via wave-uniform s_load per k (scalar pipe).
__global__ __launch_bounds__(256, 2) void eoutT_kernel(
    const float* __restrict__ e,
    const float* __restrict__ scsp,
    const float* __restrict__ Tm,      // [73][64]: Woe^T k=0..63, M2^T k=64..71, bc
    float* __restrict__ e_out)
{
    const int t   = threadIdx.x;
    const int r   = t & 63;
    const int w   = __builtin_amdgcn_readfirstlane(t >> 6);   // col group 0..3
    const int row = blockIdx.x * 64 + r;

    float ev[72];
    {
        const float* ep = e + (size_t)row * 64;
        #pragma unroll
        for (int v = 0; v < 16; ++v) {
            const float4 x = ((const float4*)ep)[v];
            ev[v*4+0] = x.x; ev[v*4+1] = x.y; ev[v*4+2] = x.z; ev[v*4+3] = x.w;
        }
        const float4 s0 = *(const float4*)(scsp + (size_t)row * 8);
        const float4 s1 = *(const float4*)(scsp + (size_t)row * 8 + 4);
        ev[64]=s0.x; ev[65]=s0.y; ev[66]=s0.z; ev[67]=s0.w;
        ev[68]=s1.x; ev[69]=s1.y; ev[70]=s1.z; ev[71]=s1.w;
    }
    const float* wbase = Tm + w * 16;              // wave-uniform
    float acc[16];
    #pragma unroll
    for (int u = 0; u < 16; ++u) acc[u] = wbase[72 * 64 + u];   // bc via s_load
    #pragma unroll
    for (int k = 0; k < 72; ++k) {
        const float* wk = wbase + k * 64;          // wave-uniform -> s_load_dwordx16
        #pragma unroll
        for (int u = 0; u < 16; ++u)
            acc[u] = fmaf(ev[k], wk[u], acc[u]);   // 16 independent FMAs
    }
    float* orow = e_out + (size_t)row * 64 + w * 16;
    #pragma unroll
    for (int u = 0; u < 4; ++u)
        *(float4*)&orow[u * 4] =
            make_float4(acc[u*4+0], acc[u*4+1], acc[u*4+2], acc[u*4+3]);
}

// Fallback eout if d_ws can't hold Tm (r10 shape).
__global__ __launch_bounds__(256, 2) void eout_kernel(
    const float* __restrict__ e,
    const float* __restrict__ scsp,
    const float* __restrict__ Woe,
    const float* __restrict__ M2g,
    float* __restrict__ e_out)
{
    __shared__ float shE[64 * 64];
    __shared__ float shS[64 * 8];
    const int t    = threadIdx.x;
    const int base = blockIdx.x * 64;
    {
        const int r = t >> 2, qq = t & 3;
        const float* ep = e + (size_t)(base + r) * 64 + qq * 16;
        #pragma unroll
        for (int u = 0; u < 4; ++u) {
            const float4 x = ((const float4*)ep)[u];
            const int cc = qq * 4 + u;
            *(float4*)&shE[r * 64 + ((cc ^ (r & 15)) << 2)] = x;
        }
    }
    if (t < 128) {
        const int r = t >> 1, pp = t & 1;
        *(float4*)&shS[r * 8 + pp * 4] =
            *(const float4*)(scsp + (size_t)(base + r) * 8 + pp * 4);
    }
    __syncthreads();
    const int w = __builtin_amdgcn_readfirstlane(t >> 6);
    const int r = t & 63;
    float sc[8];
    {
        const float4 a  = *(const float4*)&shS[r * 8];
        const float4 c4 = *(const float4*)&shS[r * 8 + 4];
        sc[0]=a.x; sc[1]=a.y; sc[2]=a.z; sc[3]=a.w;
        sc[4]=c4.x; sc[5]=c4.y; sc[6]=c4.z; sc[7]=c4.w;
    }
    float acc[16];
    #pragma unroll
    for (int u = 0; u < 16; ++u) {
        const int c = w * 16 + u;
        float s = M2g[512 + c];
        #pragma unroll
        for (int hq = 0; hq < 8; ++hq)
            s = fmaf(sc[hq], M2g[c * 8 + hq], s);
        acc[u] = s;
    }
    #pragma unroll
    for (int k0 = 0; k0 < 4; ++k0) {
        float ev[16];
        #pragma unroll
        for (int v = 0; v < 4; ++v) {
            const int cc = k0 * 4 + v;
            const float4 x = *(const float4*)&shE[r * 64 + ((cc ^ (r & 15)) << 2)];
            ev[v*4+0] = x.x; ev[v*4+1] = x.y; ev[v*4+2] = x.z; ev[v*4+3] = x.w;
        }
        #pragma unroll
        for (int u = 0; u < 16; ++u) {
            const float* wr = Woe + (w * 16 + u) * 64 + k0 * 16;
            #pragma unroll
            for (int k = 0; k < 16; ++k)
                acc[u] = fmaf(ev[k], wr[k], acc[u]);
        }
    }
    float* orow = e_out + (size_t)(base + r) * 64 + w * 16;
    #pragma unroll
    for (int u = 0; u < 4; ++u)
        *(float4*)&orow[u * 4] =
            make_float4(acc[u*4+0], acc[u*4+1], acc[u*4+2], acc[u*4+3]);
}

extern "C" void kernel_launch(void* const* d_in, const int* in_sizes, int n_in,
                              void* d_out, int out_size, void* d_ws, size_t ws_size,
                              hipStream_t stream) {
    const float* h    = (const float*)d_in[0];
    const float* e    = (const float*)d_in[1];
    const float* adj2 = (const float*)d_in[2];
    const float* rel  = (const float*)d_in[3];
    const float* Wq   = (const float*)d_in[4];  const float* bq  = (const float*)d_in[5];
    const float* Wk   = (const float*)d_in[6];  const float* bk  = (const float*)d_in[7];
    const float* Wv   = (const float*)d_in[8];  const float* bv  = (const float*)d_in[9];
    const float* Wpe  = (const float*)d_in[10]; const float* bpe = (const float*)d_in[11];
    const float* Wap  = (const float*)d_in[12]; const float* bap = (const float*)d_in[13];
    const float* Wo   = (const float*)d_in[14]; const float* bo  = (const float*)d_in[15];
    const float* Woe  = (const float*)d_in[16]; const float* boe = (const float*)d_in[17];

    float* out  = (float*)d_out;
    float* hout = out;                        // [16384*64]; holds wVg between kernels
    float* eout = out + 16384 * 64;           // [262144*64], staging (dead at eout time)
    float* Qs   = eout;
    float* Ks   = eout + 1048576;
    float* Vs   = eout + 2097152;
    float* PEs  = eout + 3145728;             // ends 5242880
    float* ws   = (float*)d_ws;
    float* scsp = ws;                         // [262144*8]
    float* M2g  = ws + 2097152;               // [576]
    float* Tm   = ws + 2098176;               // [73*64]
    const int hasT = (ws_size >= (size_t)(2098176 + 73 * 64) * sizeof(float)) ? 1 : 0;

    prep_kernel<<<dim3(82), dim3(64), 0, stream>>>(Wap, bap, Woe, boe, M2g, Tm, hasT);
    qkvpe_kernel<<<dim3(768), dim3(512), 0, stream>>>(
        h, e, Wq, bq, Wk, bk, Wv, bv, Wpe, bpe, Qs, Ks, Vs, PEs);
    attn_kernel<<<dim3(512), dim3(256), 0, stream>>>(
        Qs, Ks, Vs, PEs, adj2, rel, hout /*wVg*/, scsp);
    hout_kernel<<<dim3(256), dim3(256), 0, stream>>>(hout, Wo, bo, hout);
    if (hasT)
        eoutT_kernel<<<dim3(4096), dim3(256), 0, stream>>>(e, scsp, Tm, eout);
    else
        eout_kernel<<<dim3(4096), dim3(256), 0, stream>>>(e, scsp, Woe, M2g, eout);
}